// Round 1
// baseline (2563.842 us; speedup 1.0000x reference)
//
#include <hip/hip_runtime.h>
#include <math.h>

#define TB 256

static __device__ __forceinline__ unsigned f2o(float x) {
    unsigned b = __float_as_uint(x);
    return (b & 0x80000000u) ? ~b : (b | 0x80000000u);
}
static __device__ __forceinline__ float o2f(unsigned u) {
    return (u & 0x80000000u) ? __uint_as_float(u & 0x7FFFFFFFu) : __uint_as_float(~u);
}

static __device__ __forceinline__ int edge_src(const int* ei, int E, int e) {
    return (e < E) ? ei[e] : (e - E);
}
static __device__ __forceinline__ int edge_dst(const int* ei, int E, int e) {
    return (e < E) ? ei[E + e] : (e - E);
}

// ---------------- CSR build ----------------
__global__ void csr_count(const int* __restrict__ ei, int E, int Etot, int* __restrict__ cnt) {
    int e = blockIdx.x * blockDim.x + threadIdx.x;
    if (e >= Etot) return;
    atomicAdd(&cnt[edge_dst(ei, E, e)], 1);
}

__global__ void scan_excl(const int* __restrict__ cnt, int* __restrict__ off, int n) {
    __shared__ int sdata[TB];
    __shared__ int carry;
    int t = threadIdx.x;
    if (t == 0) { carry = 0; off[0] = 0; }
    __syncthreads();
    for (int base = 0; base < n; base += TB) {
        int v = (base + t < n) ? cnt[base + t] : 0;
        for (int d = 1; d < TB; d <<= 1) {
            sdata[t] = v; __syncthreads();
            if (t >= d) v += sdata[t - d];
            __syncthreads();
        }
        if (base + t < n) off[base + t + 1] = carry + v;
        __syncthreads();
        if (t == TB - 1) carry += v;
        __syncthreads();
    }
}

__global__ void csr_fill(const int* __restrict__ ei, int E, int Etot,
                         const int* __restrict__ off, int* __restrict__ cur,
                         int* __restrict__ eids) {
    int e = blockIdx.x * blockDim.x + threadIdx.x;
    if (e >= Etot) return;
    int d = edge_dst(ei, E, e);
    int pos = atomicAdd(&cur[d], 1);
    eids[off[d] + pos] = e;
}

// ---------------- GEMM: C[M,N] = A[M,K] @ B[K,N], fp32 ----------------
// BM=64, BN=64, BK=16, 256 threads, 4x4 per thread. N%64==0, K%16==0, M guarded.
__global__ __launch_bounds__(256) void sgemm64(const float* __restrict__ A,
                                               const float* __restrict__ B,
                                               float* __restrict__ C,
                                               int M, int N, int K) {
    __shared__ float As[16][64];
    __shared__ float Bs[16][64];
    int tid = threadIdx.x;
    int bm = blockIdx.y * 64, bn = blockIdx.x * 64;
    int tx = tid & 15, ty = tid >> 4;
    int arow = tid >> 2, acol4 = (tid & 3) * 4;
    int brow = tid >> 4, bcol4 = (tid & 15) * 4;
    float acc[4][4] = {};
    for (int k0 = 0; k0 < K; k0 += 16) {
        float4 a4;
        if (bm + arow < M) a4 = *(const float4*)(A + (size_t)(bm + arow) * K + k0 + acol4);
        else a4 = make_float4(0.f, 0.f, 0.f, 0.f);
        As[acol4 + 0][arow] = a4.x;
        As[acol4 + 1][arow] = a4.y;
        As[acol4 + 2][arow] = a4.z;
        As[acol4 + 3][arow] = a4.w;
        *(float4*)(&Bs[brow][bcol4]) = *(const float4*)(B + (size_t)(k0 + brow) * N + bn + bcol4);
        __syncthreads();
#pragma unroll
        for (int k = 0; k < 16; ++k) {
            float av[4], bv[4];
#pragma unroll
            for (int i = 0; i < 4; ++i) av[i] = As[k][ty * 4 + i];
#pragma unroll
            for (int i = 0; i < 4; ++i) bv[i] = Bs[k][tx * 4 + i];
#pragma unroll
            for (int i = 0; i < 4; ++i)
#pragma unroll
                for (int j = 0; j < 4; ++j) acc[i][j] += av[i] * bv[j];
        }
        __syncthreads();
    }
#pragma unroll
    for (int i = 0; i < 4; ++i) {
        int r = bm + ty * 4 + i;
        if (r < M) {
            float4 v = make_float4(acc[i][0], acc[i][1], acc[i][2], acc[i][3]);
            *(float4*)(C + (size_t)r * N + bn + tx * 4) = v;
        }
    }
}

// ---------------- attention scores es/ed per node ----------------
template <int H, int CPL>
__global__ __launch_bounds__(256) void attn_scores_k(const float* __restrict__ hmat,
                                                     const float* __restrict__ a_s,
                                                     const float* __restrict__ a_d,
                                                     float* __restrict__ es,
                                                     float* __restrict__ ed, int N) {
    int n = (blockIdx.x * blockDim.x + threadIdx.x) >> 6;
    int lane = threadIdx.x & 63;
    if (n >= N) return;
    const int C = CPL * 64;
    const float* row = hmat + (size_t)n * H * C;
#pragma unroll
    for (int h = 0; h < H; ++h) {
        float s = 0.f, d = 0.f;
#pragma unroll
        for (int cc = 0; cc < CPL; ++cc) {
            float v = row[h * C + cc * 64 + lane];
            s += v * a_s[h * C + cc * 64 + lane];
            d += v * a_d[h * C + cc * 64 + lane];
        }
#pragma unroll
        for (int o = 32; o; o >>= 1) {
            s += __shfl_xor(s, o);
            d += __shfl_xor(d, o);
        }
        if (lane == 0) {
            es[(size_t)n * H + h] = s;
            ed[(size_t)n * H + h] = d;
        }
    }
}

// ---------------- edge pass 1: leaky logits + segment max ----------------
template <int H>
__global__ void edge_logits(const float* __restrict__ es, const float* __restrict__ ed,
                            const int* __restrict__ ei, int E, int Etot,
                            float* __restrict__ ebuf, unsigned* __restrict__ m) {
    int e = blockIdx.x * blockDim.x + threadIdx.x;
    if (e >= Etot) return;
    int s = edge_src(ei, E, e), d = edge_dst(ei, E, e);
#pragma unroll
    for (int h = 0; h < H; ++h) {
        float v = es[(size_t)s * H + h] + ed[(size_t)d * H + h];
        v = (v > 0.f) ? v : 0.2f * v;
        ebuf[(size_t)e * H + h] = v;
        atomicMax(&m[(size_t)d * H + h], f2o(v));
    }
}

// ---------------- edge pass 2: exp + segment sum ----------------
template <int H>
__global__ void edge_soft(const int* __restrict__ ei, int E, int Etot,
                          float* __restrict__ ebuf, const unsigned* __restrict__ m,
                          float* __restrict__ den) {
    int e = blockIdx.x * blockDim.x + threadIdx.x;
    if (e >= Etot) return;
    int d = edge_dst(ei, E, e);
#pragma unroll
    for (int h = 0; h < H; ++h) {
        unsigned u = m[(size_t)d * H + h];
        float mf = u ? o2f(u) : 0.f;
        float p = expf(ebuf[(size_t)e * H + h] - mf);
        ebuf[(size_t)e * H + h] = p;
        atomicAdd(&den[(size_t)d * H + h], p);
    }
}

// ---------------- CSR aggregation: out[n] = mean_h( sum_e p*h[src] / den ) + b ---
template <int H, int CPL, bool RELU>
__global__ __launch_bounds__(256) void aggregate(const float* __restrict__ hsrc,
                                                 const float* __restrict__ p,
                                                 const float* __restrict__ den,
                                                 const int* __restrict__ off,
                                                 const int* __restrict__ eids,
                                                 const int* __restrict__ ei, int E,
                                                 const float* __restrict__ bias,
                                                 float* __restrict__ out, int N) {
    int n = (blockIdx.x * blockDim.x + threadIdx.x) >> 6;
    int lane = threadIdx.x & 63;
    if (n >= N) return;
    const int C = CPL * 64;
    float acc[H][CPL];
#pragma unroll
    for (int h = 0; h < H; ++h)
#pragma unroll
        for (int cc = 0; cc < CPL; ++cc) acc[h][cc] = 0.f;
    int j0 = off[n], j1 = off[n + 1];
    for (int j = j0; j < j1; ++j) {
        int e = eids[j];
        int s = edge_src(ei, E, e);
        const float* hrow = hsrc + (size_t)s * H * C;
#pragma unroll
        for (int h = 0; h < H; ++h) {
            float ph = p[(size_t)e * H + h];
#pragma unroll
            for (int cc = 0; cc < CPL; ++cc)
                acc[h][cc] += ph * hrow[h * C + cc * 64 + lane];
        }
    }
#pragma unroll
    for (int cc = 0; cc < CPL; ++cc) {
        float o = 0.f;
#pragma unroll
        for (int h = 0; h < H; ++h)
            o += acc[h][cc] / (den[(size_t)n * H + h] + 1e-16f);
        o = o * (1.0f / H) + bias[cc * 64 + lane];
        if (RELU) o = fmaxf(o, 0.f);
        out[(size_t)n * C + cc * 64 + lane] = o;
    }
}

// ---------------- pooling ----------------
__global__ __launch_bounds__(256) void gate_kernel(const float* __restrict__ h,
                                                   const float* __restrict__ w1,
                                                   const float* __restrict__ b1,
                                                   const float* __restrict__ w2,
                                                   const float* __restrict__ b2,
                                                   const int* __restrict__ batch,
                                                   float* __restrict__ gate,
                                                   unsigned* __restrict__ gm, int N) {
    int n = (blockIdx.x * blockDim.x + threadIdx.x) >> 6;
    int lane = threadIdx.x & 63;
    if (n >= N) return;
    float hv = h[(size_t)n * 64 + lane];
    float t = b1[lane];
    for (int c = 0; c < 64; ++c) t += __shfl(hv, c) * w1[c * 64 + lane];
    t = fmaxf(t, 0.f);
    float g = t * w2[lane];
#pragma unroll
    for (int o = 32; o; o >>= 1) g += __shfl_xor(g, o);
    g += b2[0];
    if (lane == 0) {
        gate[n] = g;
        atomicMax(&gm[batch[n]], f2o(g));
    }
}

__global__ void pool_p(const float* __restrict__ gate, const unsigned* __restrict__ gm,
                       const int* __restrict__ batch, float* __restrict__ pg,
                       float* __restrict__ gden, int N) {
    int n = blockIdx.x * blockDim.x + threadIdx.x;
    if (n >= N) return;
    int b = batch[n];
    unsigned u = gm[b];
    float mf = u ? o2f(u) : 0.f;
    float p = expf(gate[n] - mf);
    pg[n] = p;
    atomicAdd(&gden[b], p);
}

#define NODES_PER_WAVE 128
__global__ __launch_bounds__(256) void pool_sum(const float* __restrict__ h,
                                                const float* __restrict__ pg,
                                                const int* __restrict__ batch,
                                                float* __restrict__ pooled, int N) {
    int w = (blockIdx.x * blockDim.x + threadIdx.x) >> 6;
    int lane = threadIdx.x & 63;
    int start = w * NODES_PER_WAVE;
    if (start >= N) return;
    int curg = batch[start];
    float acc = 0.f;
    for (int i = 0; i < NODES_PER_WAVE; ++i) {
        int n = start + i;
        if (n >= N) break;
        int g = batch[n];
        if (g != curg) {
            atomicAdd(&pooled[curg * 64 + lane], acc);
            acc = 0.f;
            curg = g;
        }
        acc += pg[n] * h[(size_t)n * 64 + lane];
    }
    atomicAdd(&pooled[curg * 64 + lane], acc);
}

// dec_prep: normalize pooled, hd016 = pooledN @ W_d0, es16/ed16 dots. grid=16, block=64.
__global__ void dec_prep(const float* __restrict__ pooled, const float* __restrict__ gden,
                         const float* __restrict__ Wd0, const float* __restrict__ asd,
                         const float* __restrict__ add, float* __restrict__ hd016,
                         float* __restrict__ es16, float* __restrict__ ed16) {
    int g = blockIdx.x;
    int lane = threadIdx.x;
    float pn = pooled[g * 64 + lane] / (gden[g] + 1e-16f);
    float o = 0.f;
    for (int c = 0; c < 64; ++c) o += __shfl(pn, c) * Wd0[c * 64 + lane];
    hd016[g * 64 + lane] = o;
    float s = o * asd[lane], d = o * add[lane];
#pragma unroll
    for (int off = 32; off; off >>= 1) {
        s += __shfl_xor(s, off);
        d += __shfl_xor(d, off);
    }
    if (lane == 0) {
        es16[g] = s;
        ed16[g] = d;
    }
}

__global__ __launch_bounds__(256) void expand_dec(const int* __restrict__ batch,
                                                  const float* __restrict__ hd016,
                                                  const float* __restrict__ es16,
                                                  const float* __restrict__ ed16,
                                                  float* __restrict__ hd0full,
                                                  float* __restrict__ esd,
                                                  float* __restrict__ edd, int N) {
    int n = (blockIdx.x * blockDim.x + threadIdx.x) >> 6;
    int lane = threadIdx.x & 63;
    if (n >= N) return;
    int g = batch[n];
    hd0full[(size_t)n * 64 + lane] = hd016[g * 64 + lane];
    if (lane == 0) {
        esd[n] = es16[g];
        edd[n] = ed16[g];
    }
}

// ---------------- host ----------------
static inline int cdiv(int a, int b) { return (a + b - 1) / b; }

extern "C" void kernel_launch(void* const* d_in, const int* in_sizes, int n_in,
                              void* d_out, int out_size, void* d_ws, size_t ws_size,
                              hipStream_t stream) {
    const float* x      = (const float*)d_in[0];
    const int*   ei     = (const int*)  d_in[1];
    const int*   batch  = (const int*)  d_in[2];
    const float* W_e0   = (const float*)d_in[3];
    const float* a_s_e0 = (const float*)d_in[4];
    const float* a_d_e0 = (const float*)d_in[5];
    const float* b_e0   = (const float*)d_in[6];
    const float* W_e1   = (const float*)d_in[7];
    const float* a_s_e1 = (const float*)d_in[8];
    const float* a_d_e1 = (const float*)d_in[9];
    const float* b_e1   = (const float*)d_in[10];
    const float* W_d0   = (const float*)d_in[11];
    const float* a_s_d0 = (const float*)d_in[12];
    const float* a_d_d0 = (const float*)d_in[13];
    const float* b_d0   = (const float*)d_in[14];
    const float* W_d1   = (const float*)d_in[15];
    const float* a_s_d1 = (const float*)d_in[16];
    const float* a_d_d1 = (const float*)d_in[17];
    const float* b_d1   = (const float*)d_in[18];
    const float* g_w1   = (const float*)d_in[19];
    const float* g_b1   = (const float*)d_in[20];
    const float* g_w2   = (const float*)d_in[21];
    const float* g_b2   = (const float*)d_in[22];

    const int N    = in_sizes[2];
    const int E    = in_sizes[1] / 2;
    const int Etot = E + N;
    const int Din  = in_sizes[0] / N;  // 128

    // workspace carve (256B aligned)
    char* w = (char*)d_ws;
    size_t o = 0;
    auto alloc = [&](size_t bytes) -> void* {
        void* p = w + o;
        o = (o + bytes + 255) & ~(size_t)255;
        return p;
    };
    float*    h_big  = (float*)   alloc((size_t)N * 512 * 4);  // GEMM outputs
    float*    bufA   = (float*)   alloc((size_t)N * 64 * 4);   // enc0 out / dec0 out
    float*    bufB   = (float*)   alloc((size_t)N * 64 * 4);   // enc1 out / hd0full
    float*    es     = (float*)   alloc((size_t)N * 8 * 4);
    float*    ed     = (float*)   alloc((size_t)N * 8 * 4);
    unsigned* m      = (unsigned*)alloc((size_t)N * 8 * 4);
    float*    den    = (float*)   alloc((size_t)N * 8 * 4);
    float*    ebuf   = (float*)   alloc((size_t)Etot * 8 * 4);
    float*    gate   = (float*)   alloc((size_t)N * 4);        // later esd
    float*    pg     = (float*)   alloc((size_t)N * 4);        // later edd
    int*      off    = (int*)     alloc((size_t)(N + 1) * 4);
    int*      cnt    = (int*)     alloc((size_t)N * 4);        // also cursor
    int*      eids   = (int*)     alloc((size_t)Etot * 4);
    unsigned* gm     = (unsigned*)alloc(16 * 4);
    float*    gden   = (float*)   alloc(16 * 4);
    float*    pooled = (float*)   alloc(16 * 64 * 4);
    float*    hd016  = (float*)   alloc(16 * 64 * 4);
    float*    es16   = (float*)   alloc(16 * 4);
    float*    ed16   = (float*)   alloc(16 * 4);
    (void)ws_size; (void)n_in; (void)out_size;

    float* esd = gate;  // decoder per-node scores (reuse)
    float* edd = pg;

    const int nodeWaveGrid = cdiv(N, 4);     // 4 waves (nodes) per 256-block
    const int edgeGrid     = cdiv(Etot, TB);

    // ---- CSR (once, shared by all 4 GAT layers) ----
    hipMemsetAsync(cnt, 0, (size_t)N * 4, stream);
    csr_count<<<edgeGrid, TB, 0, stream>>>(ei, E, Etot, cnt);
    scan_excl<<<1, TB, 0, stream>>>(cnt, off, N);
    hipMemsetAsync(cnt, 0, (size_t)N * 4, stream);
    csr_fill<<<edgeGrid, TB, 0, stream>>>(ei, E, Etot, off, cnt, eids);

    // ---- encoder layer 0 (H=8, C=64, relu) ----
    {
        dim3 grid(512 / 64, cdiv(N, 64));
        sgemm64<<<grid, TB, 0, stream>>>(x, W_e0, h_big, N, 512, Din);
    }
    attn_scores_k<8, 1><<<nodeWaveGrid, TB, 0, stream>>>(h_big, a_s_e0, a_d_e0, es, ed, N);
    hipMemsetAsync(m, 0, (size_t)N * 8 * 4, stream);
    hipMemsetAsync(den, 0, (size_t)N * 8 * 4, stream);
    edge_logits<8><<<edgeGrid, TB, 0, stream>>>(es, ed, ei, E, Etot, ebuf, m);
    edge_soft<8><<<edgeGrid, TB, 0, stream>>>(ei, E, Etot, ebuf, m, den);
    aggregate<8, 1, true><<<nodeWaveGrid, TB, 0, stream>>>(h_big, ebuf, den, off, eids, ei, E, b_e0, bufA, N);

    // ---- encoder layer 1 (H=8, C=64, no relu) ----
    {
        dim3 grid(512 / 64, cdiv(N, 64));
        sgemm64<<<grid, TB, 0, stream>>>(bufA, W_e1, h_big, N, 512, 64);
    }
    attn_scores_k<8, 1><<<nodeWaveGrid, TB, 0, stream>>>(h_big, a_s_e1, a_d_e1, es, ed, N);
    hipMemsetAsync(m, 0, (size_t)N * 8 * 4, stream);
    hipMemsetAsync(den, 0, (size_t)N * 8 * 4, stream);
    edge_logits<8><<<edgeGrid, TB, 0, stream>>>(es, ed, ei, E, Etot, ebuf, m);
    edge_soft<8><<<edgeGrid, TB, 0, stream>>>(ei, E, Etot, ebuf, m, den);
    aggregate<8, 1, false><<<nodeWaveGrid, TB, 0, stream>>>(h_big, ebuf, den, off, eids, ei, E, b_e1, bufB, N);

    // ---- global attention pooling ----
    hipMemsetAsync(gm, 0, 16 * 4, stream);
    hipMemsetAsync(gden, 0, 16 * 4, stream);
    hipMemsetAsync(pooled, 0, 16 * 64 * 4, stream);
    gate_kernel<<<nodeWaveGrid, TB, 0, stream>>>(bufB, g_w1, g_b1, g_w2, g_b2, batch, gate, gm, N);
    pool_p<<<cdiv(N, TB), TB, 0, stream>>>(gate, gm, batch, pg, gden, N);
    pool_sum<<<cdiv(cdiv(N, NODES_PER_WAVE), 4), TB, 0, stream>>>(bufB, pg, batch, pooled, N);
    dec_prep<<<16, 64, 0, stream>>>(pooled, gden, W_d0, a_s_d0, a_d_d0, hd016, es16, ed16);
    expand_dec<<<nodeWaveGrid, TB, 0, stream>>>(batch, hd016, es16, ed16, bufB, esd, edd, N);

    // ---- decoder layer 0 (H=1, C=64, relu) ----
    hipMemsetAsync(m, 0, (size_t)N * 4, stream);
    hipMemsetAsync(den, 0, (size_t)N * 4, stream);
    edge_logits<1><<<edgeGrid, TB, 0, stream>>>(esd, edd, ei, E, Etot, ebuf, m);
    edge_soft<1><<<edgeGrid, TB, 0, stream>>>(ei, E, Etot, ebuf, m, den);
    aggregate<1, 1, true><<<nodeWaveGrid, TB, 0, stream>>>(bufB, ebuf, den, off, eids, ei, E, b_d0, bufA, N);

    // ---- decoder layer 1 (H=1, C=128, no relu) -> d_out ----
    {
        dim3 grid(128 / 64, cdiv(N, 64));
        sgemm64<<<grid, TB, 0, stream>>>(bufA, W_d1, h_big, N, 128, 64);
    }
    attn_scores_k<1, 2><<<nodeWaveGrid, TB, 0, stream>>>(h_big, a_s_d1, a_d_d1, esd, edd, N);
    hipMemsetAsync(m, 0, (size_t)N * 4, stream);
    hipMemsetAsync(den, 0, (size_t)N * 4, stream);
    edge_logits<1><<<edgeGrid, TB, 0, stream>>>(esd, edd, ei, E, Etot, ebuf, m);
    edge_soft<1><<<edgeGrid, TB, 0, stream>>>(ei, E, Etot, ebuf, m, den);
    aggregate<1, 2, false><<<nodeWaveGrid, TB, 0, stream>>>(h_big, ebuf, den, off, eids, ei, E, b_d1, (float*)d_out, N);
}

// Round 2
// 1235.266 us; speedup vs baseline: 2.0755x; 2.0755x over previous
//
#include <hip/hip_runtime.h>
#include <math.h>

#define TB 256

static __device__ __forceinline__ unsigned f2o(float x) {
    unsigned b = __float_as_uint(x);
    return (b & 0x80000000u) ? ~b : (b | 0x80000000u);
}
static __device__ __forceinline__ float o2f(unsigned u) {
    return (u & 0x80000000u) ? __uint_as_float(u & 0x7FFFFFFFu) : __uint_as_float(~u);
}

static __device__ __forceinline__ int edge_src(const int* ei, int E, int e) {
    return (e < E) ? ei[e] : (e - E);
}
static __device__ __forceinline__ int edge_dst(const int* ei, int E, int e) {
    return (e < E) ? ei[E + e] : (e - E);
}

// ---------------- CSR build ----------------
__global__ void csr_count(const int* __restrict__ ei, int E, int Etot, int* __restrict__ cnt) {
    int e = blockIdx.x * blockDim.x + threadIdx.x;
    if (e >= Etot) return;
    atomicAdd(&cnt[edge_dst(ei, E, e)], 1);
}

// 3-phase parallel exclusive scan (n <= 65536)
__global__ __launch_bounds__(256) void scan_phase1(const int* __restrict__ cnt,
                                                   int* __restrict__ incl,
                                                   int* __restrict__ bsum, int n) {
    __shared__ int sdata[256];
    int t = threadIdx.x;
    int base = blockIdx.x * 256;
    int v = (base + t < n) ? cnt[base + t] : 0;
    for (int d = 1; d < 256; d <<= 1) {
        sdata[t] = v; __syncthreads();
        if (t >= d) v += sdata[t - d];
        __syncthreads();
    }
    if (base + t < n) incl[base + t] = v;
    if (t == 255) bsum[blockIdx.x] = v;
}

__global__ void scan_phase2(int* bsum, int nb) {
    __shared__ int sdata[256];
    int t = threadIdx.x;
    int v = (t < nb) ? bsum[t] : 0;
    for (int d = 1; d < 256; d <<= 1) {
        sdata[t] = v; __syncthreads();
        if (t >= d) v += sdata[t - d];
        __syncthreads();
    }
    if (t < nb) bsum[t] = v;
}

__global__ __launch_bounds__(256) void scan_phase3(const int* __restrict__ incl,
                                                   const int* __restrict__ bsum,
                                                   int* __restrict__ off, int n) {
    int i = blockIdx.x * 256 + threadIdx.x;
    if (i < n) off[i + 1] = incl[i] + (blockIdx.x ? bsum[blockIdx.x - 1] : 0);
    if (i == 0) off[0] = 0;
}

__global__ void csr_fill(const int* __restrict__ ei, int E, int Etot,
                         const int* __restrict__ off, int* __restrict__ cur,
                         int* __restrict__ eids) {
    int e = blockIdx.x * blockDim.x + threadIdx.x;
    if (e >= Etot) return;
    int d = edge_dst(ei, E, e);
    int pos = atomicAdd(&cur[d], 1);
    eids[off[d] + pos] = e;
}

// ---------------- GEMM: C[M,N] = A[M,K] @ B[K,N], fp32 ----------------
__global__ __launch_bounds__(256) void sgemm64(const float* __restrict__ A,
                                               const float* __restrict__ B,
                                               float* __restrict__ C,
                                               int M, int N, int K) {
    __shared__ float As[16][64];
    __shared__ float Bs[16][64];
    int tid = threadIdx.x;
    int bm = blockIdx.y * 64, bn = blockIdx.x * 64;
    int tx = tid & 15, ty = tid >> 4;
    int arow = tid >> 2, acol4 = (tid & 3) * 4;
    int brow = tid >> 4, bcol4 = (tid & 15) * 4;
    float acc[4][4] = {};
    for (int k0 = 0; k0 < K; k0 += 16) {
        float4 a4;
        if (bm + arow < M) a4 = *(const float4*)(A + (size_t)(bm + arow) * K + k0 + acol4);
        else a4 = make_float4(0.f, 0.f, 0.f, 0.f);
        As[acol4 + 0][arow] = a4.x;
        As[acol4 + 1][arow] = a4.y;
        As[acol4 + 2][arow] = a4.z;
        As[acol4 + 3][arow] = a4.w;
        *(float4*)(&Bs[brow][bcol4]) = *(const float4*)(B + (size_t)(k0 + brow) * N + bn + bcol4);
        __syncthreads();
#pragma unroll
        for (int k = 0; k < 16; ++k) {
            float av[4], bv[4];
#pragma unroll
            for (int i = 0; i < 4; ++i) av[i] = As[k][ty * 4 + i];
#pragma unroll
            for (int i = 0; i < 4; ++i) bv[i] = Bs[k][tx * 4 + i];
#pragma unroll
            for (int i = 0; i < 4; ++i)
#pragma unroll
                for (int j = 0; j < 4; ++j) acc[i][j] += av[i] * bv[j];
        }
        __syncthreads();
    }
#pragma unroll
    for (int i = 0; i < 4; ++i) {
        int r = bm + ty * 4 + i;
        if (r < M) {
            float4 v = make_float4(acc[i][0], acc[i][1], acc[i][2], acc[i][3]);
            *(float4*)(C + (size_t)r * N + bn + tx * 4) = v;
        }
    }
}

// ---------------- attention scores es/ed per node ----------------
template <int H, int CPL>
__global__ __launch_bounds__(256) void attn_scores_k(const float* __restrict__ hmat,
                                                     const float* __restrict__ a_s,
                                                     const float* __restrict__ a_d,
                                                     float* __restrict__ es,
                                                     float* __restrict__ ed, int N) {
    int n = (blockIdx.x * blockDim.x + threadIdx.x) >> 6;
    int lane = threadIdx.x & 63;
    if (n >= N) return;
    const int C = CPL * 64;
    const float* row = hmat + (size_t)n * H * C;
#pragma unroll
    for (int h = 0; h < H; ++h) {
        float s = 0.f, d = 0.f;
#pragma unroll
        for (int cc = 0; cc < CPL; ++cc) {
            float v = row[h * C + cc * 64 + lane];
            s += v * a_s[h * C + cc * 64 + lane];
            d += v * a_d[h * C + cc * 64 + lane];
        }
#pragma unroll
        for (int o = 32; o; o >>= 1) {
            s += __shfl_xor(s, o);
            d += __shfl_xor(d, o);
        }
        if (lane == 0) {
            es[(size_t)n * H + h] = s;
            ed[(size_t)n * H + h] = d;
        }
    }
}

// ---------------- edge pass 1: leaky logits + segment max ----------------
template <int H>
__global__ void edge_logits(const float* __restrict__ es, const float* __restrict__ ed,
                            const int* __restrict__ ei, int E, int Etot,
                            float* __restrict__ ebuf, unsigned* __restrict__ m) {
    int e = blockIdx.x * blockDim.x + threadIdx.x;
    if (e >= Etot) return;
    int s = edge_src(ei, E, e), d = edge_dst(ei, E, e);
#pragma unroll
    for (int h = 0; h < H; ++h) {
        float v = es[(size_t)s * H + h] + ed[(size_t)d * H + h];
        v = (v > 0.f) ? v : 0.2f * v;
        ebuf[(size_t)e * H + h] = v;
        atomicMax(&m[(size_t)d * H + h], f2o(v));
    }
}

// ---------------- edge pass 2: exp + segment sum ----------------
template <int H>
__global__ void edge_soft(const int* __restrict__ ei, int E, int Etot,
                          float* __restrict__ ebuf, const unsigned* __restrict__ m,
                          float* __restrict__ den) {
    int e = blockIdx.x * blockDim.x + threadIdx.x;
    if (e >= Etot) return;
    int d = edge_dst(ei, E, e);
#pragma unroll
    for (int h = 0; h < H; ++h) {
        unsigned u = m[(size_t)d * H + h];
        float mf = u ? o2f(u) : 0.f;
        float p = expf(ebuf[(size_t)e * H + h] - mf);
        ebuf[(size_t)e * H + h] = p;
        atomicAdd(&den[(size_t)d * H + h], p);
    }
}

// ---------------- CSR aggregation ----------------
template <int H, int CPL, bool RELU>
__global__ __launch_bounds__(256) void aggregate(const float* __restrict__ hsrc,
                                                 const float* __restrict__ p,
                                                 const float* __restrict__ den,
                                                 const int* __restrict__ off,
                                                 const int* __restrict__ eids,
                                                 const int* __restrict__ ei, int E,
                                                 const float* __restrict__ bias,
                                                 float* __restrict__ out, int N) {
    int n = (blockIdx.x * blockDim.x + threadIdx.x) >> 6;
    int lane = threadIdx.x & 63;
    if (n >= N) return;
    const int C = CPL * 64;
    float acc[H][CPL];
#pragma unroll
    for (int h = 0; h < H; ++h)
#pragma unroll
        for (int cc = 0; cc < CPL; ++cc) acc[h][cc] = 0.f;
    int j0 = off[n], j1 = off[n + 1];
    for (int j = j0; j < j1; ++j) {
        int e = eids[j];
        int s = edge_src(ei, E, e);
        const float* hrow = hsrc + (size_t)s * H * C;
#pragma unroll
        for (int h = 0; h < H; ++h) {
            float ph = p[(size_t)e * H + h];
#pragma unroll
            for (int cc = 0; cc < CPL; ++cc)
                acc[h][cc] += ph * hrow[h * C + cc * 64 + lane];
        }
    }
#pragma unroll
    for (int cc = 0; cc < CPL; ++cc) {
        float o = 0.f;
#pragma unroll
        for (int h = 0; h < H; ++h)
            o += acc[h][cc] / (den[(size_t)n * H + h] + 1e-16f);
        o = o * (1.0f / H) + bias[cc * 64 + lane];
        if (RELU) o = fmaxf(o, 0.f);
        out[(size_t)n * C + cc * 64 + lane] = o;
    }
}

// ---------------- pooling ----------------
__global__ __launch_bounds__(256) void gate_kernel(const float* __restrict__ h,
                                                   const float* __restrict__ w1,
                                                   const float* __restrict__ b1,
                                                   const float* __restrict__ w2,
                                                   const float* __restrict__ b2,
                                                   float* __restrict__ gate, int N) {
    int n = (blockIdx.x * blockDim.x + threadIdx.x) >> 6;
    int lane = threadIdx.x & 63;
    if (n >= N) return;
    float hv = h[(size_t)n * 64 + lane];
    float t = b1[lane];
    for (int c = 0; c < 64; ++c) t += __shfl(hv, c) * w1[c * 64 + lane];
    t = fmaxf(t, 0.f);
    float g = t * w2[lane];
#pragma unroll
    for (int o = 32; o; o >>= 1) g += __shfl_xor(g, o);
    g += b2[0];
    if (lane == 0) gate[n] = g;
}

// grid-stride segment max with LDS pre-reduction (16 graphs)
__global__ __launch_bounds__(256) void gmax_kernel(const float* __restrict__ gate,
                                                   const int* __restrict__ batch,
                                                   unsigned* __restrict__ gm, int N) {
    __shared__ unsigned smax[16];
    int t = threadIdx.x;
    if (t < 16) smax[t] = 0u;
    __syncthreads();
    for (int i = blockIdx.x * blockDim.x + t; i < N; i += gridDim.x * blockDim.x)
        atomicMax(&smax[batch[i]], f2o(gate[i]));
    __syncthreads();
    if (t < 16 && smax[t]) atomicMax(&gm[t], smax[t]);
}

// exp + segment sum with LDS pre-reduction
__global__ __launch_bounds__(256) void pool_p(const float* __restrict__ gate,
                                              const unsigned* __restrict__ gm,
                                              const int* __restrict__ batch,
                                              float* __restrict__ pg,
                                              float* __restrict__ gden, int N) {
    __shared__ float part[16];
    int t = threadIdx.x;
    if (t < 16) part[t] = 0.f;
    __syncthreads();
    int n = blockIdx.x * blockDim.x + t;
    if (n < N) {
        int b = batch[n];
        unsigned u = gm[b];
        float mf = u ? o2f(u) : 0.f;
        float p = expf(gate[n] - mf);
        pg[n] = p;
        atomicAdd(&part[b], p);
    }
    __syncthreads();
    if (t < 16 && part[t] != 0.f) atomicAdd(&gden[t], part[t]);
}

#define NODES_PER_WAVE 128
__global__ __launch_bounds__(256) void pool_sum(const float* __restrict__ h,
                                                const float* __restrict__ pg,
                                                const int* __restrict__ batch,
                                                float* __restrict__ pooled, int N) {
    int w = (blockIdx.x * blockDim.x + threadIdx.x) >> 6;
    int lane = threadIdx.x & 63;
    int start = w * NODES_PER_WAVE;
    if (start >= N) return;
    int curg = batch[start];
    float acc = 0.f;
    for (int i = 0; i < NODES_PER_WAVE; ++i) {
        int n = start + i;
        if (n >= N) break;
        int g = batch[n];
        if (g != curg) {
            atomicAdd(&pooled[curg * 64 + lane], acc);
            acc = 0.f;
            curg = g;
        }
        acc += pg[n] * h[(size_t)n * 64 + lane];
    }
    atomicAdd(&pooled[curg * 64 + lane], acc);
}

__global__ void dec_prep(const float* __restrict__ pooled, const float* __restrict__ gden,
                         const float* __restrict__ Wd0, const float* __restrict__ asd,
                         const float* __restrict__ add, float* __restrict__ hd016,
                         float* __restrict__ es16, float* __restrict__ ed16) {
    int g = blockIdx.x;
    int lane = threadIdx.x;
    float pn = pooled[g * 64 + lane] / (gden[g] + 1e-16f);
    float o = 0.f;
    for (int c = 0; c < 64; ++c) o += __shfl(pn, c) * Wd0[c * 64 + lane];
    hd016[g * 64 + lane] = o;
    float s = o * asd[lane], d = o * add[lane];
#pragma unroll
    for (int off = 32; off; off >>= 1) {
        s += __shfl_xor(s, off);
        d += __shfl_xor(d, off);
    }
    if (lane == 0) {
        es16[g] = s;
        ed16[g] = d;
    }
}

__global__ __launch_bounds__(256) void expand_dec(const int* __restrict__ batch,
                                                  const float* __restrict__ hd016,
                                                  const float* __restrict__ es16,
                                                  const float* __restrict__ ed16,
                                                  float* __restrict__ hd0full,
                                                  float* __restrict__ esd,
                                                  float* __restrict__ edd, int N) {
    int n = (blockIdx.x * blockDim.x + threadIdx.x) >> 6;
    int lane = threadIdx.x & 63;
    if (n >= N) return;
    int g = batch[n];
    hd0full[(size_t)n * 64 + lane] = hd016[g * 64 + lane];
    if (lane == 0) {
        esd[n] = es16[g];
        edd[n] = ed16[g];
    }
}

// ---------------- host ----------------
static inline int cdiv(int a, int b) { return (a + b - 1) / b; }

extern "C" void kernel_launch(void* const* d_in, const int* in_sizes, int n_in,
                              void* d_out, int out_size, void* d_ws, size_t ws_size,
                              hipStream_t stream) {
    const float* x      = (const float*)d_in[0];
    const int*   ei     = (const int*)  d_in[1];
    const int*   batch  = (const int*)  d_in[2];
    const float* W_e0   = (const float*)d_in[3];
    const float* a_s_e0 = (const float*)d_in[4];
    const float* a_d_e0 = (const float*)d_in[5];
    const float* b_e0   = (const float*)d_in[6];
    const float* W_e1   = (const float*)d_in[7];
    const float* a_s_e1 = (const float*)d_in[8];
    const float* a_d_e1 = (const float*)d_in[9];
    const float* b_e1   = (const float*)d_in[10];
    const float* W_d0   = (const float*)d_in[11];
    const float* a_s_d0 = (const float*)d_in[12];
    const float* a_d_d0 = (const float*)d_in[13];
    const float* b_d0   = (const float*)d_in[14];
    const float* W_d1   = (const float*)d_in[15];
    const float* a_s_d1 = (const float*)d_in[16];
    const float* a_d_d1 = (const float*)d_in[17];
    const float* b_d1   = (const float*)d_in[18];
    const float* g_w1   = (const float*)d_in[19];
    const float* g_b1   = (const float*)d_in[20];
    const float* g_w2   = (const float*)d_in[21];
    const float* g_b2   = (const float*)d_in[22];

    const int N    = in_sizes[2];
    const int E    = in_sizes[1] / 2;
    const int Etot = E + N;
    const int Din  = in_sizes[0] / N;  // 128

    char* w = (char*)d_ws;
    size_t o = 0;
    auto alloc = [&](size_t bytes) -> void* {
        void* p = w + o;
        o = (o + bytes + 255) & ~(size_t)255;
        return p;
    };
    float*    h_big  = (float*)   alloc((size_t)N * 512 * 4);
    float*    bufA   = (float*)   alloc((size_t)N * 64 * 4);
    float*    bufB   = (float*)   alloc((size_t)N * 64 * 4);
    float*    es     = (float*)   alloc((size_t)N * 8 * 4);
    float*    ed     = (float*)   alloc((size_t)N * 8 * 4);
    unsigned* m      = (unsigned*)alloc((size_t)N * 8 * 4);
    float*    den    = (float*)   alloc((size_t)N * 8 * 4);
    float*    ebuf   = (float*)   alloc((size_t)Etot * 8 * 4);
    float*    gate   = (float*)   alloc((size_t)N * 4);
    float*    pg     = (float*)   alloc((size_t)N * 4);
    int*      off    = (int*)     alloc((size_t)(N + 1) * 4);
    int*      cnt    = (int*)     alloc((size_t)N * 4);
    int*      eids   = (int*)     alloc((size_t)Etot * 4);
    int*      bsum   = (int*)     alloc(256 * 4);
    unsigned* gm     = (unsigned*)alloc(16 * 4);
    float*    gden   = (float*)   alloc(16 * 4);
    float*    pooled = (float*)   alloc(16 * 64 * 4);
    float*    hd016  = (float*)   alloc(16 * 64 * 4);
    float*    es16   = (float*)   alloc(16 * 4);
    float*    ed16   = (float*)   alloc(16 * 4);
    (void)ws_size; (void)n_in; (void)out_size;

    float* esd = gate;
    float* edd = pg;

    const int nodeWaveGrid = cdiv(N, 4);
    const int edgeGrid     = cdiv(Etot, TB);
    const int scanBlocks   = cdiv(N, 256);

    // ---- CSR ----
    hipMemsetAsync(cnt, 0, (size_t)N * 4, stream);
    csr_count<<<edgeGrid, TB, 0, stream>>>(ei, E, Etot, cnt);
    scan_phase1<<<scanBlocks, 256, 0, stream>>>(cnt, eids /*temp incl*/, bsum, N);
    scan_phase2<<<1, 256, 0, stream>>>(bsum, scanBlocks);
    scan_phase3<<<scanBlocks, 256, 0, stream>>>(eids, bsum, off, N);
    hipMemsetAsync(cnt, 0, (size_t)N * 4, stream);
    csr_fill<<<edgeGrid, TB, 0, stream>>>(ei, E, Etot, off, cnt, eids);

    // ---- encoder layer 0 ----
    {
        dim3 grid(512 / 64, cdiv(N, 64));
        sgemm64<<<grid, TB, 0, stream>>>(x, W_e0, h_big, N, 512, Din);
    }
    attn_scores_k<8, 1><<<nodeWaveGrid, TB, 0, stream>>>(h_big, a_s_e0, a_d_e0, es, ed, N);
    hipMemsetAsync(m, 0, (size_t)N * 8 * 4, stream);
    hipMemsetAsync(den, 0, (size_t)N * 8 * 4, stream);
    edge_logits<8><<<edgeGrid, TB, 0, stream>>>(es, ed, ei, E, Etot, ebuf, m);
    edge_soft<8><<<edgeGrid, TB, 0, stream>>>(ei, E, Etot, ebuf, m, den);
    aggregate<8, 1, true><<<nodeWaveGrid, TB, 0, stream>>>(h_big, ebuf, den, off, eids, ei, E, b_e0, bufA, N);

    // ---- encoder layer 1 ----
    {
        dim3 grid(512 / 64, cdiv(N, 64));
        sgemm64<<<grid, TB, 0, stream>>>(bufA, W_e1, h_big, N, 512, 64);
    }
    attn_scores_k<8, 1><<<nodeWaveGrid, TB, 0, stream>>>(h_big, a_s_e1, a_d_e1, es, ed, N);
    hipMemsetAsync(m, 0, (size_t)N * 8 * 4, stream);
    hipMemsetAsync(den, 0, (size_t)N * 8 * 4, stream);
    edge_logits<8><<<edgeGrid, TB, 0, stream>>>(es, ed, ei, E, Etot, ebuf, m);
    edge_soft<8><<<edgeGrid, TB, 0, stream>>>(ei, E, Etot, ebuf, m, den);
    aggregate<8, 1, false><<<nodeWaveGrid, TB, 0, stream>>>(h_big, ebuf, den, off, eids, ei, E, b_e1, bufB, N);

    // ---- pooling ----
    hipMemsetAsync(gm, 0, 16 * 4, stream);
    hipMemsetAsync(gden, 0, 16 * 4, stream);
    hipMemsetAsync(pooled, 0, 16 * 64 * 4, stream);
    gate_kernel<<<nodeWaveGrid, TB, 0, stream>>>(bufB, g_w1, g_b1, g_w2, g_b2, gate, N);
    gmax_kernel<<<256, TB, 0, stream>>>(gate, batch, gm, N);
    pool_p<<<cdiv(N, TB), TB, 0, stream>>>(gate, gm, batch, pg, gden, N);
    pool_sum<<<cdiv(cdiv(N, NODES_PER_WAVE), 4), TB, 0, stream>>>(bufB, pg, batch, pooled, N);
    dec_prep<<<16, 64, 0, stream>>>(pooled, gden, W_d0, a_s_d0, a_d_d0, hd016, es16, ed16);
    expand_dec<<<nodeWaveGrid, TB, 0, stream>>>(batch, hd016, es16, ed16, bufB, esd, edd, N);

    // ---- decoder layer 0 ----
    hipMemsetAsync(m, 0, (size_t)N * 4, stream);
    hipMemsetAsync(den, 0, (size_t)N * 4, stream);
    edge_logits<1><<<edgeGrid, TB, 0, stream>>>(esd, edd, ei, E, Etot, ebuf, m);
    edge_soft<1><<<edgeGrid, TB, 0, stream>>>(ei, E, Etot, ebuf, m, den);
    aggregate<1, 1, true><<<nodeWaveGrid, TB, 0, stream>>>(bufB, ebuf, den, off, eids, ei, E, b_d0, bufA, N);

    // ---- decoder layer 1 -> d_out ----
    {
        dim3 grid(128 / 64, cdiv(N, 64));
        sgemm64<<<grid, TB, 0, stream>>>(bufA, W_d1, h_big, N, 128, 64);
    }
    attn_scores_k<1, 2><<<nodeWaveGrid, TB, 0, stream>>>(h_big, a_s_d1, a_d_d1, esd, edd, N);
    hipMemsetAsync(m, 0, (size_t)N * 4, stream);
    hipMemsetAsync(den, 0, (size_t)N * 4, stream);
    edge_logits<1><<<edgeGrid, TB, 0, stream>>>(esd, edd, ei, E, Etot, ebuf, m);
    edge_soft<1><<<edgeGrid, TB, 0, stream>>>(ei, E, Etot, ebuf, m, den);
    aggregate<1, 2, false><<<nodeWaveGrid, TB, 0, stream>>>(h_big, ebuf, den, off, eids, ei, E, b_d1, (float*)d_out, N);
}

// Round 3
// 854.551 us; speedup vs baseline: 3.0002x; 1.4455x over previous
//
#include <hip/hip_runtime.h>
#include <math.h>

#define TB 256

static __device__ __forceinline__ unsigned f2o(float x) {
    unsigned b = __float_as_uint(x);
    return (b & 0x80000000u) ? ~b : (b | 0x80000000u);
}
static __device__ __forceinline__ float o2f(unsigned u) {
    return (u & 0x80000000u) ? __uint_as_float(u & 0x7FFFFFFFu) : __uint_as_float(~u);
}

static __device__ __forceinline__ int edge_src(const int* ei, int E, int e) {
    return (e < E) ? ei[e] : (e - E);
}
static __device__ __forceinline__ int edge_dst(const int* ei, int E, int e) {
    return (e < E) ? ei[E + e] : (e - E);
}

// ---------------- CSR build ----------------
__global__ void csr_count(const int* __restrict__ ei, int E, int Etot, int* __restrict__ cnt) {
    int e = blockIdx.x * blockDim.x + threadIdx.x;
    if (e >= Etot) return;
    atomicAdd(&cnt[edge_dst(ei, E, e)], 1);
}

__global__ __launch_bounds__(256) void scan_phase1(const int* __restrict__ cnt,
                                                   int* __restrict__ incl,
                                                   int* __restrict__ bsum, int n) {
    __shared__ int sdata[256];
    int t = threadIdx.x;
    int base = blockIdx.x * 256;
    int v = (base + t < n) ? cnt[base + t] : 0;
    for (int d = 1; d < 256; d <<= 1) {
        sdata[t] = v; __syncthreads();
        if (t >= d) v += sdata[t - d];
        __syncthreads();
    }
    if (base + t < n) incl[base + t] = v;
    if (t == 255) bsum[blockIdx.x] = v;
}

__global__ void scan_phase2(int* bsum, int nb) {
    __shared__ int sdata[256];
    int t = threadIdx.x;
    int v = (t < nb) ? bsum[t] : 0;
    for (int d = 1; d < 256; d <<= 1) {
        sdata[t] = v; __syncthreads();
        if (t >= d) v += sdata[t - d];
        __syncthreads();
    }
    if (t < nb) bsum[t] = v;
}

__global__ __launch_bounds__(256) void scan_phase3(const int* __restrict__ incl,
                                                   const int* __restrict__ bsum,
                                                   int* __restrict__ off, int n) {
    int i = blockIdx.x * 256 + threadIdx.x;
    if (i < n) off[i + 1] = incl[i] + (blockIdx.x ? bsum[blockIdx.x - 1] : 0);
    if (i == 0) off[0] = 0;
}

__global__ void csr_fill(const int* __restrict__ ei, int E, int Etot,
                         const int* __restrict__ off, int* __restrict__ cur,
                         int* __restrict__ eids) {
    int e = blockIdx.x * blockDim.x + threadIdx.x;
    if (e >= Etot) return;
    int d = edge_dst(ei, E, e);
    int pos = atomicAdd(&cur[d], 1);
    eids[off[d] + pos] = e;
}

// ---------------- GEMM: C[M,N] = A[M,K] @ B[K,N], fp32 ----------------
__global__ __launch_bounds__(256) void sgemm64(const float* __restrict__ A,
                                               const float* __restrict__ B,
                                               float* __restrict__ C,
                                               int M, int N, int K) {
    __shared__ float As[16][64];
    __shared__ float Bs[16][64];
    int tid = threadIdx.x;
    int bm = blockIdx.y * 64, bn = blockIdx.x * 64;
    int tx = tid & 15, ty = tid >> 4;
    int arow = tid >> 2, acol4 = (tid & 3) * 4;
    int brow = tid >> 4, bcol4 = (tid & 15) * 4;
    float acc[4][4] = {};
    for (int k0 = 0; k0 < K; k0 += 16) {
        float4 a4;
        if (bm + arow < M) a4 = *(const float4*)(A + (size_t)(bm + arow) * K + k0 + acol4);
        else a4 = make_float4(0.f, 0.f, 0.f, 0.f);
        As[acol4 + 0][arow] = a4.x;
        As[acol4 + 1][arow] = a4.y;
        As[acol4 + 2][arow] = a4.z;
        As[acol4 + 3][arow] = a4.w;
        *(float4*)(&Bs[brow][bcol4]) = *(const float4*)(B + (size_t)(k0 + brow) * N + bn + bcol4);
        __syncthreads();
#pragma unroll
        for (int k = 0; k < 16; ++k) {
            float av[4], bv[4];
#pragma unroll
            for (int i = 0; i < 4; ++i) av[i] = As[k][ty * 4 + i];
#pragma unroll
            for (int i = 0; i < 4; ++i) bv[i] = Bs[k][tx * 4 + i];
#pragma unroll
            for (int i = 0; i < 4; ++i)
#pragma unroll
                for (int j = 0; j < 4; ++j) acc[i][j] += av[i] * bv[j];
        }
        __syncthreads();
    }
#pragma unroll
    for (int i = 0; i < 4; ++i) {
        int r = bm + ty * 4 + i;
        if (r < M) {
            float4 v = make_float4(acc[i][0], acc[i][1], acc[i][2], acc[i][3]);
            *(float4*)(C + (size_t)r * N + bn + tx * 4) = v;
        }
    }
}

// ---------------- attention scores es/ed per node ----------------
template <int H, int CPL>
__global__ __launch_bounds__(256) void attn_scores_k(const float* __restrict__ hmat,
                                                     const float* __restrict__ a_s,
                                                     const float* __restrict__ a_d,
                                                     float* __restrict__ es,
                                                     float* __restrict__ ed, int N) {
    int n = (blockIdx.x * blockDim.x + threadIdx.x) >> 6;
    int lane = threadIdx.x & 63;
    if (n >= N) return;
    const int C = CPL * 64;
    const float* row = hmat + (size_t)n * H * C;
#pragma unroll
    for (int h = 0; h < H; ++h) {
        float s = 0.f, d = 0.f;
#pragma unroll
        for (int cc = 0; cc < CPL; ++cc) {
            float v = row[h * C + cc * 64 + lane];
            s += v * a_s[h * C + cc * 64 + lane];
            d += v * a_d[h * C + cc * 64 + lane];
        }
#pragma unroll
        for (int o = 32; o; o >>= 1) {
            s += __shfl_xor(s, o);
            d += __shfl_xor(d, o);
        }
        if (lane == 0) {
            es[(size_t)n * H + h] = s;
            ed[(size_t)n * H + h] = d;
        }
    }
}

// ---------------- FUSED per-dst softmax + aggregation (no atomics) ----------------
// One wave per dst node. Pass 1: per-head max over in-edges (lanes 0..H-1).
// Pass 2: recompute logit, p=exp(v-m), accumulate denom (in-register) and
// alpha-weighted gather of h[src] (lane = channel). INDIRECT: src row index
// is remapped through `rmap` (decoder-0: 16-row pooled table).
template <int H, int CPL, bool RELU, bool INDIRECT>
__global__ __launch_bounds__(256) void gat_gather(const float* __restrict__ hsrc,
                                                  const float* __restrict__ es,
                                                  const float* __restrict__ ed,
                                                  const int* __restrict__ off,
                                                  const int* __restrict__ eids,
                                                  const int* __restrict__ ei, int E,
                                                  const int* __restrict__ rmap,
                                                  const float* __restrict__ bias,
                                                  float* __restrict__ out, int N) {
    int n = (blockIdx.x * blockDim.x + threadIdx.x) >> 6;
    int lane = threadIdx.x & 63;
    if (n >= N) return;
    const int C = CPL * 64;
    int j0 = off[n], j1 = off[n + 1];

    float ed_h = (lane < H) ? ed[(size_t)n * H + lane] : 0.f;

    // pass 1: per-head max
    float m_h = -INFINITY;
    for (int j = j0; j < j1; ++j) {
        int e = eids[j];
        int s = edge_src(ei, E, e);
        if (lane < H) {
            float v = es[(size_t)s * H + lane] + ed_h;
            v = (v > 0.f) ? v : 0.2f * v;
            m_h = fmaxf(m_h, v);
        }
    }

    // pass 2: exp + denom + weighted gather
    float acc[H][CPL];
#pragma unroll
    for (int h = 0; h < H; ++h)
#pragma unroll
        for (int cc = 0; cc < CPL; ++cc) acc[h][cc] = 0.f;
    float den_h = 0.f;
    for (int j = j0; j < j1; ++j) {
        int e = eids[j];
        int s = edge_src(ei, E, e);
        float p_mine = 0.f;
        if (lane < H) {
            float v = es[(size_t)s * H + lane] + ed_h;
            v = (v > 0.f) ? v : 0.2f * v;
            p_mine = expf(v - m_h);
            den_h += p_mine;
        }
        int srow = INDIRECT ? rmap[s] : s;
        const float* hrow = hsrc + (size_t)srow * H * C;
#pragma unroll
        for (int h = 0; h < H; ++h) {
            float ph = __shfl(p_mine, h);
#pragma unroll
            for (int cc = 0; cc < CPL; ++cc)
                acc[h][cc] += ph * hrow[h * C + cc * 64 + lane];
        }
    }

#pragma unroll
    for (int cc = 0; cc < CPL; ++cc) {
        float o = 0.f;
#pragma unroll
        for (int h = 0; h < H; ++h)
            o += acc[h][cc] / (__shfl(den_h, h) + 1e-16f);
        o = o * (1.0f / H) + bias[cc * 64 + lane];
        if (RELU) o = fmaxf(o, 0.f);
        out[(size_t)n * C + cc * 64 + lane] = o;
    }
}

// ---------------- pooling ----------------
__global__ __launch_bounds__(256) void gate_kernel(const float* __restrict__ h,
                                                   const float* __restrict__ w1,
                                                   const float* __restrict__ b1,
                                                   const float* __restrict__ w2,
                                                   const float* __restrict__ b2,
                                                   float* __restrict__ gate, int N) {
    int n = (blockIdx.x * blockDim.x + threadIdx.x) >> 6;
    int lane = threadIdx.x & 63;
    if (n >= N) return;
    float hv = h[(size_t)n * 64 + lane];
    float t = b1[lane];
    for (int c = 0; c < 64; ++c) t += __shfl(hv, c) * w1[c * 64 + lane];
    t = fmaxf(t, 0.f);
    float g = t * w2[lane];
#pragma unroll
    for (int o = 32; o; o >>= 1) g += __shfl_xor(g, o);
    g += b2[0];
    if (lane == 0) gate[n] = g;
}

__global__ __launch_bounds__(256) void gmax_kernel(const float* __restrict__ gate,
                                                   const int* __restrict__ batch,
                                                   unsigned* __restrict__ gm, int N) {
    __shared__ unsigned smax[16];
    int t = threadIdx.x;
    if (t < 16) smax[t] = 0u;
    __syncthreads();
    for (int i = blockIdx.x * blockDim.x + t; i < N; i += gridDim.x * blockDim.x)
        atomicMax(&smax[batch[i]], f2o(gate[i]));
    __syncthreads();
    if (t < 16 && smax[t]) atomicMax(&gm[t], smax[t]);
}

__global__ __launch_bounds__(256) void pool_p(const float* __restrict__ gate,
                                              const unsigned* __restrict__ gm,
                                              const int* __restrict__ batch,
                                              float* __restrict__ pg,
                                              float* __restrict__ gden, int N) {
    __shared__ float part[16];
    int t = threadIdx.x;
    if (t < 16) part[t] = 0.f;
    __syncthreads();
    int n = blockIdx.x * blockDim.x + t;
    if (n < N) {
        int b = batch[n];
        unsigned u = gm[b];
        float mf = u ? o2f(u) : 0.f;
        float p = expf(gate[n] - mf);
        pg[n] = p;
        atomicAdd(&part[b], p);
    }
    __syncthreads();
    if (t < 16 && part[t] != 0.f) atomicAdd(&gden[t], part[t]);
}

#define NODES_PER_WAVE 128
__global__ __launch_bounds__(256) void pool_sum(const float* __restrict__ h,
                                                const float* __restrict__ pg,
                                                const int* __restrict__ batch,
                                                float* __restrict__ pooled, int N) {
    int w = (blockIdx.x * blockDim.x + threadIdx.x) >> 6;
    int lane = threadIdx.x & 63;
    int start = w * NODES_PER_WAVE;
    if (start >= N) return;
    int curg = batch[start];
    float acc = 0.f;
    for (int i = 0; i < NODES_PER_WAVE; ++i) {
        int n = start + i;
        if (n >= N) break;
        int g = batch[n];
        if (g != curg) {
            atomicAdd(&pooled[curg * 64 + lane], acc);
            acc = 0.f;
            curg = g;
        }
        acc += pg[n] * h[(size_t)n * 64 + lane];
    }
    atomicAdd(&pooled[curg * 64 + lane], acc);
}

__global__ void dec_prep(const float* __restrict__ pooled, const float* __restrict__ gden,
                         const float* __restrict__ Wd0, const float* __restrict__ asd,
                         const float* __restrict__ add, float* __restrict__ hd016,
                         float* __restrict__ es16, float* __restrict__ ed16) {
    int g = blockIdx.x;
    int lane = threadIdx.x;
    float pn = pooled[g * 64 + lane] / (gden[g] + 1e-16f);
    float o = 0.f;
    for (int c = 0; c < 64; ++c) o += __shfl(pn, c) * Wd0[c * 64 + lane];
    hd016[g * 64 + lane] = o;
    float s = o * asd[lane], d = o * add[lane];
#pragma unroll
    for (int off = 32; off; off >>= 1) {
        s += __shfl_xor(s, off);
        d += __shfl_xor(d, off);
    }
    if (lane == 0) {
        es16[g] = s;
        ed16[g] = d;
    }
}

// per-node decoder-0 scores: esd[n]=es16[batch[n]], edd[n]=ed16[batch[n]]
__global__ void expand_scores(const int* __restrict__ batch,
                              const float* __restrict__ es16,
                              const float* __restrict__ ed16,
                              float* __restrict__ esd,
                              float* __restrict__ edd, int N) {
    int n = blockIdx.x * blockDim.x + threadIdx.x;
    if (n >= N) return;
    int g = batch[n];
    esd[n] = es16[g];
    edd[n] = ed16[g];
}

// ---------------- host ----------------
static inline int cdiv(int a, int b) { return (a + b - 1) / b; }

extern "C" void kernel_launch(void* const* d_in, const int* in_sizes, int n_in,
                              void* d_out, int out_size, void* d_ws, size_t ws_size,
                              hipStream_t stream) {
    const float* x      = (const float*)d_in[0];
    const int*   ei     = (const int*)  d_in[1];
    const int*   batch  = (const int*)  d_in[2];
    const float* W_e0   = (const float*)d_in[3];
    const float* a_s_e0 = (const float*)d_in[4];
    const float* a_d_e0 = (const float*)d_in[5];
    const float* b_e0   = (const float*)d_in[6];
    const float* W_e1   = (const float*)d_in[7];
    const float* a_s_e1 = (const float*)d_in[8];
    const float* a_d_e1 = (const float*)d_in[9];
    const float* b_e1   = (const float*)d_in[10];
    const float* W_d0   = (const float*)d_in[11];
    const float* a_s_d0 = (const float*)d_in[12];
    const float* a_d_d0 = (const float*)d_in[13];
    const float* b_d0   = (const float*)d_in[14];
    const float* W_d1   = (const float*)d_in[15];
    const float* a_s_d1 = (const float*)d_in[16];
    const float* a_d_d1 = (const float*)d_in[17];
    const float* b_d1   = (const float*)d_in[18];
    const float* g_w1   = (const float*)d_in[19];
    const float* g_b1   = (const float*)d_in[20];
    const float* g_w2   = (const float*)d_in[21];
    const float* g_b2   = (const float*)d_in[22];

    const int N    = in_sizes[2];
    const int E    = in_sizes[1] / 2;
    const int Etot = E + N;
    const int Din  = in_sizes[0] / N;  // 128

    char* w = (char*)d_ws;
    size_t o = 0;
    auto alloc = [&](size_t bytes) -> void* {
        void* p = w + o;
        o = (o + bytes + 255) & ~(size_t)255;
        return p;
    };
    float*    h_big  = (float*)   alloc((size_t)N * 512 * 4);
    float*    bufA   = (float*)   alloc((size_t)N * 64 * 4);
    float*    bufB   = (float*)   alloc((size_t)N * 64 * 4);
    float*    es     = (float*)   alloc((size_t)N * 8 * 4);
    float*    ed     = (float*)   alloc((size_t)N * 8 * 4);
    float*    gate   = (float*)   alloc((size_t)N * 4);
    float*    pg     = (float*)   alloc((size_t)N * 4);
    int*      off    = (int*)     alloc((size_t)(N + 1) * 4);
    int*      cnt    = (int*)     alloc((size_t)N * 4);
    int*      eids   = (int*)     alloc((size_t)Etot * 4);
    int*      bsum   = (int*)     alloc(256 * 4);
    unsigned* gm     = (unsigned*)alloc(16 * 4);
    float*    gden   = (float*)   alloc(16 * 4);
    float*    pooled = (float*)   alloc(16 * 64 * 4);
    float*    hd016  = (float*)   alloc(16 * 64 * 4);
    float*    es16   = (float*)   alloc(16 * 4);
    float*    ed16   = (float*)   alloc(16 * 4);
    (void)ws_size; (void)n_in; (void)out_size;

    float* esd = gate;  // decoder per-node scores (reuse)
    float* edd = pg;

    const int nodeWaveGrid = cdiv(N, 4);
    const int edgeGrid     = cdiv(Etot, TB);
    const int scanBlocks   = cdiv(N, 256);

    // ---- CSR ----
    hipMemsetAsync(cnt, 0, (size_t)N * 4, stream);
    csr_count<<<edgeGrid, TB, 0, stream>>>(ei, E, Etot, cnt);
    scan_phase1<<<scanBlocks, 256, 0, stream>>>(cnt, eids /*temp incl*/, bsum, N);
    scan_phase2<<<1, 256, 0, stream>>>(bsum, scanBlocks);
    scan_phase3<<<scanBlocks, 256, 0, stream>>>(eids, bsum, off, N);
    hipMemsetAsync(cnt, 0, (size_t)N * 4, stream);
    csr_fill<<<edgeGrid, TB, 0, stream>>>(ei, E, Etot, off, cnt, eids);

    // ---- encoder layer 0 (H=8, relu) ----
    {
        dim3 grid(512 / 64, cdiv(N, 64));
        sgemm64<<<grid, TB, 0, stream>>>(x, W_e0, h_big, N, 512, Din);
    }
    attn_scores_k<8, 1><<<nodeWaveGrid, TB, 0, stream>>>(h_big, a_s_e0, a_d_e0, es, ed, N);
    gat_gather<8, 1, true, false><<<nodeWaveGrid, TB, 0, stream>>>(
        h_big, es, ed, off, eids, ei, E, nullptr, b_e0, bufA, N);

    // ---- encoder layer 1 (H=8) ----
    {
        dim3 grid(512 / 64, cdiv(N, 64));
        sgemm64<<<grid, TB, 0, stream>>>(bufA, W_e1, h_big, N, 512, 64);
    }
    attn_scores_k<8, 1><<<nodeWaveGrid, TB, 0, stream>>>(h_big, a_s_e1, a_d_e1, es, ed, N);
    gat_gather<8, 1, false, false><<<nodeWaveGrid, TB, 0, stream>>>(
        h_big, es, ed, off, eids, ei, E, nullptr, b_e1, bufB, N);

    // ---- pooling ----
    hipMemsetAsync(gm, 0, 16 * 4, stream);
    hipMemsetAsync(gden, 0, 16 * 4, stream);
    hipMemsetAsync(pooled, 0, 16 * 64 * 4, stream);
    gate_kernel<<<nodeWaveGrid, TB, 0, stream>>>(bufB, g_w1, g_b1, g_w2, g_b2, gate, N);
    gmax_kernel<<<256, TB, 0, stream>>>(gate, batch, gm, N);
    pool_p<<<cdiv(N, TB), TB, 0, stream>>>(gate, gm, batch, pg, gden, N);
    pool_sum<<<cdiv(cdiv(N, NODES_PER_WAVE), 4), TB, 0, stream>>>(bufB, pg, batch, pooled, N);
    dec_prep<<<16, 64, 0, stream>>>(pooled, gden, W_d0, a_s_d0, a_d_d0, hd016, es16, ed16);
    expand_scores<<<cdiv(N, TB), TB, 0, stream>>>(batch, es16, ed16, esd, edd, N);

    // ---- decoder layer 0 (H=1, relu): gather from 16-row hd016 via batch[src] ----
    gat_gather<1, 1, true, true><<<nodeWaveGrid, TB, 0, stream>>>(
        hd016, esd, edd, off, eids, ei, E, batch, b_d0, bufA, N);

    // ---- decoder layer 1 (H=1, C=128) -> d_out ----
    {
        dim3 grid(128 / 64, cdiv(N, 64));
        sgemm64<<<grid, TB, 0, stream>>>(bufA, W_d1, h_big, N, 128, 64);
    }
    attn_scores_k<1, 2><<<nodeWaveGrid, TB, 0, stream>>>(h_big, a_s_d1, a_d_d1, esd, edd, N);
    gat_gather<1, 2, false, false><<<nodeWaveGrid, TB, 0, stream>>>(
        h_big, esd, edd, off, eids, ei, E, nullptr, b_d1, (float*)d_out, N);
}

// Round 4
// 655.645 us; speedup vs baseline: 3.9104x; 1.3034x over previous
//
#include <hip/hip_runtime.h>
#include <hip/hip_fp16.h>
#include <math.h>

#define TB 256

static __device__ __forceinline__ unsigned f2o(float x) {
    unsigned b = __float_as_uint(x);
    return (b & 0x80000000u) ? ~b : (b | 0x80000000u);
}
static __device__ __forceinline__ float o2f(unsigned u) {
    return (u & 0x80000000u) ? __uint_as_float(u & 0x7FFFFFFFu) : __uint_as_float(~u);
}

static __device__ __forceinline__ int edge_src(const int* ei, int E, int e) {
    return (e < E) ? ei[e] : (e - E);
}
static __device__ __forceinline__ int edge_dst(const int* ei, int E, int e) {
    return (e < E) ? ei[E + e] : (e - E);
}

// ---------------- CSR build ----------------
__global__ void csr_count(const int* __restrict__ ei, int E, int Etot, int* __restrict__ cnt) {
    int e = blockIdx.x * blockDim.x + threadIdx.x;
    if (e >= Etot) return;
    atomicAdd(&cnt[edge_dst(ei, E, e)], 1);
}

__global__ __launch_bounds__(256) void scan_phase1(const int* __restrict__ cnt,
                                                   int* __restrict__ incl,
                                                   int* __restrict__ bsum, int n) {
    __shared__ int sdata[256];
    int t = threadIdx.x;
    int base = blockIdx.x * 256;
    int v = (base + t < n) ? cnt[base + t] : 0;
    for (int d = 1; d < 256; d <<= 1) {
        sdata[t] = v; __syncthreads();
        if (t >= d) v += sdata[t - d];
        __syncthreads();
    }
    if (base + t < n) incl[base + t] = v;
    if (t == 255) bsum[blockIdx.x] = v;
}

__global__ void scan_phase2(int* bsum, int nb) {
    __shared__ int sdata[256];
    int t = threadIdx.x;
    int v = (t < nb) ? bsum[t] : 0;
    for (int d = 1; d < 256; d <<= 1) {
        sdata[t] = v; __syncthreads();
        if (t >= d) v += sdata[t - d];
        __syncthreads();
    }
    if (t < nb) bsum[t] = v;
}

__global__ __launch_bounds__(256) void scan_phase3(const int* __restrict__ incl,
                                                   const int* __restrict__ bsum,
                                                   int* __restrict__ off, int n) {
    int i = blockIdx.x * 256 + threadIdx.x;
    if (i < n) off[i + 1] = incl[i] + (blockIdx.x ? bsum[blockIdx.x - 1] : 0);
    if (i == 0) off[0] = 0;
}

// stores SRC node id directly (removes one indirection in gathers)
__global__ void csr_fill(const int* __restrict__ ei, int E, int Etot,
                         const int* __restrict__ off, int* __restrict__ cur,
                         int* __restrict__ esrc) {
    int e = blockIdx.x * blockDim.x + threadIdx.x;
    if (e >= Etot) return;
    int d = edge_dst(ei, E, e);
    int pos = atomicAdd(&cur[d], 1);
    esrc[off[d] + pos] = edge_src(ei, E, e);
}

// ---------------- GEMM: C[M,N] = A[M,K] @ B[K,N], fp32 acc -> fp16 store ----
__global__ __launch_bounds__(256) void sgemm16(const float* __restrict__ A,
                                               const float* __restrict__ B,
                                               __half* __restrict__ C,
                                               int M, int N, int K) {
    __shared__ float As[16][64];
    __shared__ float Bs[16][64];
    int tid = threadIdx.x;
    int bm = blockIdx.y * 64, bn = blockIdx.x * 64;
    int tx = tid & 15, ty = tid >> 4;
    int arow = tid >> 2, acol4 = (tid & 3) * 4;
    int brow = tid >> 4, bcol4 = (tid & 15) * 4;
    float acc[4][4] = {};
    for (int k0 = 0; k0 < K; k0 += 16) {
        float4 a4;
        if (bm + arow < M) a4 = *(const float4*)(A + (size_t)(bm + arow) * K + k0 + acol4);
        else a4 = make_float4(0.f, 0.f, 0.f, 0.f);
        As[acol4 + 0][arow] = a4.x;
        As[acol4 + 1][arow] = a4.y;
        As[acol4 + 2][arow] = a4.z;
        As[acol4 + 3][arow] = a4.w;
        *(float4*)(&Bs[brow][bcol4]) = *(const float4*)(B + (size_t)(k0 + brow) * N + bn + bcol4);
        __syncthreads();
#pragma unroll
        for (int k = 0; k < 16; ++k) {
            float av[4], bv[4];
#pragma unroll
            for (int i = 0; i < 4; ++i) av[i] = As[k][ty * 4 + i];
#pragma unroll
            for (int i = 0; i < 4; ++i) bv[i] = Bs[k][tx * 4 + i];
#pragma unroll
            for (int i = 0; i < 4; ++i)
#pragma unroll
                for (int j = 0; j < 4; ++j) acc[i][j] += av[i] * bv[j];
        }
        __syncthreads();
    }
#pragma unroll
    for (int i = 0; i < 4; ++i) {
        int r = bm + ty * 4 + i;
        if (r < M) {
            __half2* dst = (__half2*)(C + (size_t)r * N + bn + tx * 4);
            dst[0] = __floats2half2_rn(acc[i][0], acc[i][1]);
            dst[1] = __floats2half2_rn(acc[i][2], acc[i][3]);
        }
    }
}

// ---------------- attention scores from fp16 h (one wave per node) -----------
// lane covers VPL=H*C/64 contiguous positions, all within head hd=lane/LPH.
template <int H, int C>
__global__ __launch_bounds__(256) void attn_scores_h(const __half* __restrict__ hmat,
                                                     const float* __restrict__ a_s,
                                                     const float* __restrict__ a_d,
                                                     float* __restrict__ es,
                                                     float* __restrict__ ed, int N) {
    constexpr int HC = H * C;
    constexpr int VPL = HC / 64;   // values per lane
    constexpr int LPH = 64 / H;    // lanes per head
    int n = (blockIdx.x * blockDim.x + threadIdx.x) >> 6;
    int lane = threadIdx.x & 63;
    if (n >= N) return;
    int hd = lane / LPH;
    const __half* row = hmat + (size_t)n * HC + VPL * lane;
    float v[VPL];
    if constexpr (VPL == 8) {
        uint4 raw = *(const uint4*)row;
        const __half* hv = (const __half*)&raw;
#pragma unroll
        for (int k = 0; k < 8; ++k) v[k] = __half2float(hv[k]);
    } else {
        __half2 raw = *(const __half2*)row;
        v[0] = __low2float(raw);
        v[1] = __high2float(raw);
    }
    float s = 0.f, d = 0.f;
#pragma unroll
    for (int k = 0; k < VPL; ++k) {
        s += v[k] * a_s[VPL * lane + k];
        d += v[k] * a_d[VPL * lane + k];
    }
#pragma unroll
    for (int o = 1; o < LPH; o <<= 1) {
        s += __shfl_xor(s, o);
        d += __shfl_xor(d, o);
    }
    if ((lane & (LPH - 1)) == 0) {
        es[(size_t)n * H + hd] = s;
        ed[(size_t)n * H + hd] = d;
    }
}

// ---------------- FUSED per-dst softmax + aggregation from fp16 h ------------
template <int H, int C, bool RELU>
__global__ __launch_bounds__(256) void gat_gather_h(const __half* __restrict__ hsrc,
                                                    const float* __restrict__ es,
                                                    const float* __restrict__ ed,
                                                    const int* __restrict__ off,
                                                    const int* __restrict__ esrc,
                                                    const float* __restrict__ bias,
                                                    float* __restrict__ out, int N) {
    constexpr int HC = H * C;
    constexpr int VPL = HC / 64;
    constexpr int LPH = 64 / H;
    int n = (blockIdx.x * blockDim.x + threadIdx.x) >> 6;
    int lane = threadIdx.x & 63;
    if (n >= N) return;
    int hd = lane / LPH;
    int j0 = off[n], j1 = off[n + 1];

    float ed_h = (lane < H) ? ed[(size_t)n * H + lane] : 0.f;

    // pass 1: per-head max (lanes 0..H-1)
    float m_h = -INFINITY;
    for (int j = j0; j < j1; ++j) {
        int s = esrc[j];
        if (lane < H) {
            float v = es[(size_t)s * H + lane] + ed_h;
            v = (v > 0.f) ? v : 0.2f * v;
            m_h = fmaxf(m_h, v);
        }
    }

    // pass 2: exp + denom + weighted vector gather
    float acc[VPL] = {};
    float den_h = 0.f;
    for (int j = j0; j < j1; ++j) {
        int s = esrc[j];
        float pm = 0.f;
        if (lane < H) {
            float v = es[(size_t)s * H + lane] + ed_h;
            v = (v > 0.f) ? v : 0.2f * v;
            pm = expf(v - m_h);
            den_h += pm;
        }
        float a = __shfl(pm, hd);
        const __half* row = hsrc + (size_t)s * HC + VPL * lane;
        if constexpr (VPL == 8) {
            uint4 raw = *(const uint4*)row;
            const __half* hv = (const __half*)&raw;
#pragma unroll
            for (int k = 0; k < 8; ++k) acc[k] += a * __half2float(hv[k]);
        } else {
            __half2 raw = *(const __half2*)row;
            acc[0] += a * __low2float(raw);
            acc[1] += a * __high2float(raw);
        }
    }

    // normalize per head, then sum heads via butterfly over lane bits >= log2(LPH)
    float dv = __shfl(den_h, hd) + 1e-16f;
#pragma unroll
    for (int k = 0; k < VPL; ++k) acc[k] /= dv;
#pragma unroll
    for (int o = LPH; o < 64; o <<= 1)
#pragma unroll
        for (int k = 0; k < VPL; ++k) acc[k] += __shfl_xor(acc[k], o);

    if (lane < C / VPL) {
        int cbase = VPL * lane;
        float r[VPL];
#pragma unroll
        for (int k = 0; k < VPL; ++k) {
            float o2 = acc[k] * (1.0f / H) + bias[cbase + k];
            if (RELU) o2 = fmaxf(o2, 0.f);
            r[k] = o2;
        }
        float* dst = out + (size_t)n * C + cbase;
        if constexpr (VPL == 8) {
            *(float4*)(dst) = make_float4(r[0], r[1], r[2], r[3]);
            *(float4*)(dst + 4) = make_float4(r[4], r[5], r[6], r[7]);
        } else {
            *(float2*)(dst) = make_float2(r[0], r[1]);
        }
    }
}

// ---------------- fp32 gather for decoder-0 (16-row table, INDIRECT) ---------
__global__ __launch_bounds__(256) void gat_gather_d0(const float* __restrict__ hsrc,
                                                     const float* __restrict__ es,
                                                     const float* __restrict__ ed,
                                                     const int* __restrict__ off,
                                                     const int* __restrict__ esrc,
                                                     const int* __restrict__ rmap,
                                                     const float* __restrict__ bias,
                                                     float* __restrict__ out, int N) {
    int n = (blockIdx.x * blockDim.x + threadIdx.x) >> 6;
    int lane = threadIdx.x & 63;
    if (n >= N) return;
    int j0 = off[n], j1 = off[n + 1];
    float ed_h = (lane == 0) ? ed[n] : 0.f;
    float m_h = -INFINITY;
    for (int j = j0; j < j1; ++j) {
        int s = esrc[j];
        if (lane == 0) {
            float v = es[s] + ed_h;
            v = (v > 0.f) ? v : 0.2f * v;
            m_h = fmaxf(m_h, v);
        }
    }
    float acc = 0.f, den_h = 0.f;
    for (int j = j0; j < j1; ++j) {
        int s = esrc[j];
        float pm = 0.f;
        if (lane == 0) {
            float v = es[s] + ed_h;
            v = (v > 0.f) ? v : 0.2f * v;
            pm = expf(v - m_h);
            den_h += pm;
        }
        float a = __shfl(pm, 0);
        acc += a * hsrc[(size_t)rmap[s] * 64 + lane];
    }
    float dv = __shfl(den_h, 0) + 1e-16f;
    float o = acc / dv + bias[lane];
    o = fmaxf(o, 0.f);
    out[(size_t)n * 64 + lane] = o;
}

// ---------------- pooling ----------------
__global__ __launch_bounds__(256) void gate_kernel(const float* __restrict__ h,
                                                   const float* __restrict__ w1,
                                                   const float* __restrict__ b1,
                                                   const float* __restrict__ w2,
                                                   const float* __restrict__ b2,
                                                   float* __restrict__ gate, int N) {
    int n = (blockIdx.x * blockDim.x + threadIdx.x) >> 6;
    int lane = threadIdx.x & 63;
    if (n >= N) return;
    float hv = h[(size_t)n * 64 + lane];
    float t = b1[lane];
    for (int c = 0; c < 64; ++c) t += __shfl(hv, c) * w1[c * 64 + lane];
    t = fmaxf(t, 0.f);
    float g = t * w2[lane];
#pragma unroll
    for (int o = 32; o; o >>= 1) g += __shfl_xor(g, o);
    g += b2[0];
    if (lane == 0) gate[n] = g;
}

__global__ __launch_bounds__(256) void gmax_kernel(const float* __restrict__ gate,
                                                   const int* __restrict__ batch,
                                                   unsigned* __restrict__ gm, int N) {
    __shared__ unsigned smax[16];
    int t = threadIdx.x;
    if (t < 16) smax[t] = 0u;
    __syncthreads();
    for (int i = blockIdx.x * blockDim.x + t; i < N; i += gridDim.x * blockDim.x)
        atomicMax(&smax[batch[i]], f2o(gate[i]));
    __syncthreads();
    if (t < 16 && smax[t]) atomicMax(&gm[t], smax[t]);
}

__global__ __launch_bounds__(256) void pool_p(const float* __restrict__ gate,
                                              const unsigned* __restrict__ gm,
                                              const int* __restrict__ batch,
                                              float* __restrict__ pg,
                                              float* __restrict__ gden, int N) {
    __shared__ float part[16];
    int t = threadIdx.x;
    if (t < 16) part[t] = 0.f;
    __syncthreads();
    int n = blockIdx.x * blockDim.x + t;
    if (n < N) {
        int b = batch[n];
        unsigned u = gm[b];
        float mf = u ? o2f(u) : 0.f;
        float p = expf(gate[n] - mf);
        pg[n] = p;
        atomicAdd(&part[b], p);
    }
    __syncthreads();
    if (t < 16 && part[t] != 0.f) atomicAdd(&gden[t], part[t]);
}

#define NODES_PER_WAVE 128
__global__ __launch_bounds__(256) void pool_sum(const float* __restrict__ h,
                                                const float* __restrict__ pg,
                                                const int* __restrict__ batch,
                                                float* __restrict__ pooled, int N) {
    int w = (blockIdx.x * blockDim.x + threadIdx.x) >> 6;
    int lane = threadIdx.x & 63;
    int start = w * NODES_PER_WAVE;
    if (start >= N) return;
    int curg = batch[start];
    float acc = 0.f;
    for (int i = 0; i < NODES_PER_WAVE; ++i) {
        int n = start + i;
        if (n >= N) break;
        int g = batch[n];
        if (g != curg) {
            atomicAdd(&pooled[curg * 64 + lane], acc);
            acc = 0.f;
            curg = g;
        }
        acc += pg[n] * h[(size_t)n * 64 + lane];
    }
    atomicAdd(&pooled[curg * 64 + lane], acc);
}

__global__ void dec_prep(const float* __restrict__ pooled, const float* __restrict__ gden,
                         const float* __restrict__ Wd0, const float* __restrict__ asd,
                         const float* __restrict__ add, float* __restrict__ hd016,
                         float* __restrict__ es16, float* __restrict__ ed16) {
    int g = blockIdx.x;
    int lane = threadIdx.x;
    float pn = pooled[g * 64 + lane] / (gden[g] + 1e-16f);
    float o = 0.f;
    for (int c = 0; c < 64; ++c) o += __shfl(pn, c) * Wd0[c * 64 + lane];
    hd016[g * 64 + lane] = o;
    float s = o * asd[lane], d = o * add[lane];
#pragma unroll
    for (int off = 32; off; off >>= 1) {
        s += __shfl_xor(s, off);
        d += __shfl_xor(d, off);
    }
    if (lane == 0) {
        es16[g] = s;
        ed16[g] = d;
    }
}

__global__ void expand_scores(const int* __restrict__ batch,
                              const float* __restrict__ es16,
                              const float* __restrict__ ed16,
                              float* __restrict__ esd,
                              float* __restrict__ edd, int N) {
    int n = blockIdx.x * blockDim.x + threadIdx.x;
    if (n >= N) return;
    int g = batch[n];
    esd[n] = es16[g];
    edd[n] = ed16[g];
}

// ---------------- host ----------------
static inline int cdiv(int a, int b) { return (a + b - 1) / b; }

extern "C" void kernel_launch(void* const* d_in, const int* in_sizes, int n_in,
                              void* d_out, int out_size, void* d_ws, size_t ws_size,
                              hipStream_t stream) {
    const float* x      = (const float*)d_in[0];
    const int*   ei     = (const int*)  d_in[1];
    const int*   batch  = (const int*)  d_in[2];
    const float* W_e0   = (const float*)d_in[3];
    const float* a_s_e0 = (const float*)d_in[4];
    const float* a_d_e0 = (const float*)d_in[5];
    const float* b_e0   = (const float*)d_in[6];
    const float* W_e1   = (const float*)d_in[7];
    const float* a_s_e1 = (const float*)d_in[8];
    const float* a_d_e1 = (const float*)d_in[9];
    const float* b_e1   = (const float*)d_in[10];
    const float* W_d0   = (const float*)d_in[11];
    const float* a_s_d0 = (const float*)d_in[12];
    const float* a_d_d0 = (const float*)d_in[13];
    const float* b_d0   = (const float*)d_in[14];
    const float* W_d1   = (const float*)d_in[15];
    const float* a_s_d1 = (const float*)d_in[16];
    const float* a_d_d1 = (const float*)d_in[17];
    const float* b_d1   = (const float*)d_in[18];
    const float* g_w1   = (const float*)d_in[19];
    const float* g_b1   = (const float*)d_in[20];
    const float* g_w2   = (const float*)d_in[21];
    const float* g_b2   = (const float*)d_in[22];

    const int N    = in_sizes[2];
    const int E    = in_sizes[1] / 2;
    const int Etot = E + N;
    const int Din  = in_sizes[0] / N;  // 128

    char* w = (char*)d_ws;
    size_t o = 0;
    auto alloc = [&](size_t bytes) -> void* {
        void* p = w + o;
        o = (o + bytes + 255) & ~(size_t)255;
        return p;
    };
    __half*   h16    = (__half*)  alloc((size_t)N * 512 * 2);
    float*    bufA   = (float*)   alloc((size_t)N * 64 * 4);
    float*    bufB   = (float*)   alloc((size_t)N * 64 * 4);
    float*    es     = (float*)   alloc((size_t)N * 8 * 4);
    float*    ed     = (float*)   alloc((size_t)N * 8 * 4);
    float*    gate   = (float*)   alloc((size_t)N * 4);
    float*    pg     = (float*)   alloc((size_t)N * 4);
    int*      off    = (int*)     alloc((size_t)(N + 1) * 4);
    int*      cnt    = (int*)     alloc((size_t)N * 4);
    int*      esrc   = (int*)     alloc((size_t)Etot * 4);
    int*      bsum   = (int*)     alloc(256 * 4);
    unsigned* gm     = (unsigned*)alloc(16 * 4);
    float*    gden   = (float*)   alloc(16 * 4);
    float*    pooled = (float*)   alloc(16 * 64 * 4);
    float*    hd016  = (float*)   alloc(16 * 64 * 4);
    float*    es16   = (float*)   alloc(16 * 4);
    float*    ed16   = (float*)   alloc(16 * 4);
    (void)ws_size; (void)n_in; (void)out_size;

    float* esd = gate;  // decoder per-node scores (reuse)
    float* edd = pg;

    const int nodeWaveGrid = cdiv(N, 4);
    const int edgeGrid     = cdiv(Etot, TB);
    const int scanBlocks   = cdiv(N, 256);

    // ---- CSR ----
    hipMemsetAsync(cnt, 0, (size_t)N * 4, stream);
    csr_count<<<edgeGrid, TB, 0, stream>>>(ei, E, Etot, cnt);
    scan_phase1<<<scanBlocks, 256, 0, stream>>>(cnt, esrc /*temp incl*/, bsum, N);
    scan_phase2<<<1, 256, 0, stream>>>(bsum, scanBlocks);
    scan_phase3<<<scanBlocks, 256, 0, stream>>>(esrc, bsum, off, N);
    hipMemsetAsync(cnt, 0, (size_t)N * 4, stream);
    csr_fill<<<edgeGrid, TB, 0, stream>>>(ei, E, Etot, off, cnt, esrc);

    // ---- encoder layer 0 (H=8, relu) ----
    {
        dim3 grid(512 / 64, cdiv(N, 64));
        sgemm16<<<grid, TB, 0, stream>>>(x, W_e0, h16, N, 512, Din);
    }
    attn_scores_h<8, 64><<<nodeWaveGrid, TB, 0, stream>>>(h16, a_s_e0, a_d_e0, es, ed, N);
    gat_gather_h<8, 64, true><<<nodeWaveGrid, TB, 0, stream>>>(
        h16, es, ed, off, esrc, b_e0, bufA, N);

    // ---- encoder layer 1 (H=8) ----
    {
        dim3 grid(512 / 64, cdiv(N, 64));
        sgemm16<<<grid, TB, 0, stream>>>(bufA, W_e1, h16, N, 512, 64);
    }
    attn_scores_h<8, 64><<<nodeWaveGrid, TB, 0, stream>>>(h16, a_s_e1, a_d_e1, es, ed, N);
    gat_gather_h<8, 64, false><<<nodeWaveGrid, TB, 0, stream>>>(
        h16, es, ed, off, esrc, b_e1, bufB, N);

    // ---- pooling ----
    hipMemsetAsync(gm, 0, 16 * 4, stream);
    hipMemsetAsync(gden, 0, 16 * 4, stream);
    hipMemsetAsync(pooled, 0, 16 * 64 * 4, stream);
    gate_kernel<<<nodeWaveGrid, TB, 0, stream>>>(bufB, g_w1, g_b1, g_w2, g_b2, gate, N);
    gmax_kernel<<<256, TB, 0, stream>>>(gate, batch, gm, N);
    pool_p<<<cdiv(N, TB), TB, 0, stream>>>(gate, gm, batch, pg, gden, N);
    pool_sum<<<cdiv(cdiv(N, NODES_PER_WAVE), 4), TB, 0, stream>>>(bufB, pg, batch, pooled, N);
    dec_prep<<<16, 64, 0, stream>>>(pooled, gden, W_d0, a_s_d0, a_d_d0, hd016, es16, ed16);
    expand_scores<<<cdiv(N, TB), TB, 0, stream>>>(batch, es16, ed16, esd, edd, N);

    // ---- decoder layer 0 (H=1, relu): gather from 16-row hd016 via batch[src] ----
    gat_gather_d0<<<nodeWaveGrid, TB, 0, stream>>>(
        hd016, esd, edd, off, esrc, batch, b_d0, bufA, N);

    // ---- decoder layer 1 (H=1, C=128) -> d_out ----
    {
        dim3 grid(128 / 64, cdiv(N, 64));
        sgemm16<<<grid, TB, 0, stream>>>(bufA, W_d1, h16, N, 128, 64);
    }
    attn_scores_h<1, 128><<<nodeWaveGrid, TB, 0, stream>>>(h16, a_s_d1, a_d_d1, esd, edd, N);
    gat_gather_h<1, 128, false><<<nodeWaveGrid, TB, 0, stream>>>(
        h16, esd, edd, off, esrc, b_d1, (float*)d_out, N);
}

// Round 5
// 564.447 us; speedup vs baseline: 4.5422x; 1.1616x over previous
//
#include <hip/hip_runtime.h>
#include <hip/hip_fp16.h>
#include <math.h>

#define TB 256

typedef _Float16 half8v __attribute__((ext_vector_type(8)));
typedef float float4v __attribute__((ext_vector_type(4)));

static __device__ __forceinline__ unsigned f2o(float x) {
    unsigned b = __float_as_uint(x);
    return (b & 0x80000000u) ? ~b : (b | 0x80000000u);
}
static __device__ __forceinline__ float o2f(unsigned u) {
    return (u & 0x80000000u) ? __uint_as_float(u & 0x7FFFFFFFu) : __uint_as_float(~u);
}

static __device__ __forceinline__ int edge_src(const int* ei, int E, int e) {
    return (e < E) ? ei[e] : (e - E);
}
static __device__ __forceinline__ int edge_dst(const int* ei, int E, int e) {
    return (e < E) ? ei[E + e] : (e - E);
}

// ---------------- CSR build ----------------
__global__ void csr_count(const int* __restrict__ ei, int E, int Etot, int* __restrict__ cnt) {
    int e = blockIdx.x * blockDim.x + threadIdx.x;
    if (e >= Etot) return;
    atomicAdd(&cnt[edge_dst(ei, E, e)], 1);
}

__global__ __launch_bounds__(256) void scan_phase1(const int* __restrict__ cnt,
                                                   int* __restrict__ incl,
                                                   int* __restrict__ bsum, int n) {
    __shared__ int sdata[256];
    int t = threadIdx.x;
    int base = blockIdx.x * 256;
    int v = (base + t < n) ? cnt[base + t] : 0;
    for (int d = 1; d < 256; d <<= 1) {
        sdata[t] = v; __syncthreads();
        if (t >= d) v += sdata[t - d];
        __syncthreads();
    }
    if (base + t < n) incl[base + t] = v;
    if (t == 255) bsum[blockIdx.x] = v;
}

__global__ void scan_phase2(int* bsum, int nb) {
    __shared__ int sdata[256];
    int t = threadIdx.x;
    int v = (t < nb) ? bsum[t] : 0;
    for (int d = 1; d < 256; d <<= 1) {
        sdata[t] = v; __syncthreads();
        if (t >= d) v += sdata[t - d];
        __syncthreads();
    }
    if (t < nb) bsum[t] = v;
}

__global__ __launch_bounds__(256) void scan_phase3(const int* __restrict__ incl,
                                                   const int* __restrict__ bsum,
                                                   int* __restrict__ off, int n) {
    int i = blockIdx.x * 256 + threadIdx.x;
    if (i < n) off[i + 1] = incl[i] + (blockIdx.x ? bsum[blockIdx.x - 1] : 0);
    if (i == 0) off[0] = 0;
}

__global__ void csr_fill(const int* __restrict__ ei, int E, int Etot,
                         const int* __restrict__ off, int* __restrict__ cur,
                         int* __restrict__ esrc) {
    int e = blockIdx.x * blockDim.x + threadIdx.x;
    if (e >= Etot) return;
    int d = edge_dst(ei, E, e);
    int pos = atomicAdd(&cur[d], 1);
    esrc[off[d] + pos] = edge_src(ei, E, e);
}

// ---------------- prep: fp32 -> fp16 casts ----------------
__global__ void cast_f2h(const float* __restrict__ in, __half* __restrict__ out, int n) {
    int i2 = (blockIdx.x * blockDim.x + threadIdx.x) * 2;
    if (i2 + 1 < n) {
        float2 v = *(const float2*)(in + i2);
        *(__half2*)(out + i2) = __floats2half2_rn(v.x, v.y);
    } else if (i2 < n) {
        out[i2] = __float2half(in[i2]);
    }
}

// WT[nn][kk] = W[kk][nn], fp16
__global__ void transpose_cast(const float* __restrict__ W, __half* __restrict__ WT,
                               int K, int N) {
    int i = blockIdx.x * blockDim.x + threadIdx.x;
    if (i >= N * K) return;
    int nn = i / K, kk = i % K;
    WT[i] = __float2half(W[kk * N + nn]);
}

// ---------------- MFMA GEMM: C[M,N] = A[M,K] @ B[K,N] ----------------
// A fp16 [M][K] row-major, BT fp16 [N][K] (B transposed), C fp16 [M][N].
// 64x64 tile, 256 threads (4 waves), mfma_f32_16x16x32_f16.
// Fragment fill uses the consistent-permutation identity: slot (g,j) of A and
// B both hold logical k = k0 + 8g + j, so any symmetric HW k-map yields the
// correct dot product. C/D layout: col=lane&15, row=4*(lane>>4)+reg (verified).
template <int K>
__global__ __launch_bounds__(256) void gemm_mfma(const __half* __restrict__ A,
                                                 const __half* __restrict__ BT,
                                                 __half* __restrict__ C,
                                                 int M, int N) {
    constexpr int KP = K + 8;  // pad: row stride 272/144 B, banks spread
    __shared__ __align__(16) __half As[64 * KP];
    __shared__ __align__(16) __half Bs[64 * KP];
    int tid = threadIdx.x;
    int bm = blockIdx.y * 64, bn = blockIdx.x * 64;
    constexpr int LPR = K / 8;  // b128 loads per row
    for (int idx = tid; idx < 64 * LPR; idx += 256) {
        int row = idx / LPR, koff = (idx % LPR) * 8;
        uint4 v = make_uint4(0u, 0u, 0u, 0u);
        int gr = bm + row;
        if (gr < M) v = *(const uint4*)(A + (size_t)gr * K + koff);
        *(uint4*)(&As[row * KP + koff]) = v;
        uint4 wv = *(const uint4*)(BT + (size_t)(bn + row) * K + koff);
        *(uint4*)(&Bs[row * KP + koff]) = wv;
    }
    __syncthreads();
    int wv_ = tid >> 6, l = tid & 63;
    int lr = l & 15, g = l >> 4;
    float4v acc[4] = {{0.f, 0.f, 0.f, 0.f}, {0.f, 0.f, 0.f, 0.f},
                      {0.f, 0.f, 0.f, 0.f}, {0.f, 0.f, 0.f, 0.f}};
    const __half* ap = &As[(16 * wv_ + lr) * KP + 8 * g];
    const __half* bp = &Bs[lr * KP + 8 * g];
#pragma unroll
    for (int k0 = 0; k0 < K; k0 += 32) {
        half8v af = *reinterpret_cast<const half8v*>(ap + k0);
#pragma unroll
        for (int nt = 0; nt < 4; ++nt) {
            half8v bf = *reinterpret_cast<const half8v*>(bp + nt * 16 * KP + k0);
            acc[nt] = __builtin_amdgcn_mfma_f32_16x16x32_f16(af, bf, acc[nt], 0, 0, 0);
        }
    }
#pragma unroll
    for (int nt = 0; nt < 4; ++nt) {
#pragma unroll
        for (int r = 0; r < 4; ++r) {
            int grow = bm + 16 * wv_ + 4 * g + r;
            if (grow < M)
                C[(size_t)grow * N + bn + nt * 16 + lr] = __float2half(acc[nt][r]);
        }
    }
}

// ---------------- attention scores from fp16 h (one wave per node) -----------
template <int H, int C>
__global__ __launch_bounds__(256) void attn_scores_h(const __half* __restrict__ hmat,
                                                     const float* __restrict__ a_s,
                                                     const float* __restrict__ a_d,
                                                     float* __restrict__ es,
                                                     float* __restrict__ ed, int N) {
    constexpr int HC = H * C;
    constexpr int VPL = HC / 64;
    constexpr int LPH = 64 / H;
    int n = (blockIdx.x * blockDim.x + threadIdx.x) >> 6;
    int lane = threadIdx.x & 63;
    if (n >= N) return;
    int hd = lane / LPH;
    const __half* row = hmat + (size_t)n * HC + VPL * lane;
    float v[VPL];
    if constexpr (VPL == 8) {
        uint4 raw = *(const uint4*)row;
        const __half* hv = (const __half*)&raw;
#pragma unroll
        for (int k = 0; k < 8; ++k) v[k] = __half2float(hv[k]);
    } else {
        __half2 raw = *(const __half2*)row;
        v[0] = __low2float(raw);
        v[1] = __high2float(raw);
    }
    float s = 0.f, d = 0.f;
#pragma unroll
    for (int k = 0; k < VPL; ++k) {
        s += v[k] * a_s[VPL * lane + k];
        d += v[k] * a_d[VPL * lane + k];
    }
#pragma unroll
    for (int o = 1; o < LPH; o <<= 1) {
        s += __shfl_xor(s, o);
        d += __shfl_xor(d, o);
    }
    if ((lane & (LPH - 1)) == 0) {
        es[(size_t)n * H + hd] = s;
        ed[(size_t)n * H + hd] = d;
    }
}

// ---------------- FUSED per-dst softmax + aggregation from fp16 h ------------
template <int H, int C, bool RELU, typename OUT>
__global__ __launch_bounds__(256) void gat_gather_h(const __half* __restrict__ hsrc,
                                                    const float* __restrict__ es,
                                                    const float* __restrict__ ed,
                                                    const int* __restrict__ off,
                                                    const int* __restrict__ esrc,
                                                    const float* __restrict__ bias,
                                                    OUT* __restrict__ out, int N) {
    constexpr int HC = H * C;
    constexpr int VPL = HC / 64;
    constexpr int LPH = 64 / H;
    int n = (blockIdx.x * blockDim.x + threadIdx.x) >> 6;
    int lane = threadIdx.x & 63;
    if (n >= N) return;
    int hd = lane / LPH;
    int j0 = off[n], j1 = off[n + 1];

    float ed_h = (lane < H) ? ed[(size_t)n * H + lane] : 0.f;

    float m_h = -INFINITY;
    for (int j = j0; j < j1; ++j) {
        int s = esrc[j];
        if (lane < H) {
            float v = es[(size_t)s * H + lane] + ed_h;
            v = (v > 0.f) ? v : 0.2f * v;
            m_h = fmaxf(m_h, v);
        }
    }

    float acc[VPL] = {};
    float den_h = 0.f;
    for (int j = j0; j < j1; ++j) {
        int s = esrc[j];
        float pm = 0.f;
        if (lane < H) {
            float v = es[(size_t)s * H + lane] + ed_h;
            v = (v > 0.f) ? v : 0.2f * v;
            pm = expf(v - m_h);
            den_h += pm;
        }
        float a = __shfl(pm, hd);
        const __half* row = hsrc + (size_t)s * HC + VPL * lane;
        if constexpr (VPL == 8) {
            uint4 raw = *(const uint4*)row;
            const __half* hv = (const __half*)&raw;
#pragma unroll
            for (int k = 0; k < 8; ++k) acc[k] += a * __half2float(hv[k]);
        } else {
            __half2 raw = *(const __half2*)row;
            acc[0] += a * __low2float(raw);
            acc[1] += a * __high2float(raw);
        }
    }

    float dv = __shfl(den_h, hd) + 1e-16f;
#pragma unroll
    for (int k = 0; k < VPL; ++k) acc[k] /= dv;
#pragma unroll
    for (int o = LPH; o < 64; o <<= 1)
#pragma unroll
        for (int k = 0; k < VPL; ++k) acc[k] += __shfl_xor(acc[k], o);

    if (lane < C / VPL) {
        int cbase = VPL * lane;
        float r[VPL];
#pragma unroll
        for (int k = 0; k < VPL; ++k) {
            float o2 = acc[k] * (1.0f / H) + bias[cbase + k];
            if (RELU) o2 = fmaxf(o2, 0.f);
            r[k] = o2;
        }
        OUT* dst = out + (size_t)n * C + cbase;
        if constexpr (VPL == 8) {
            if constexpr (sizeof(OUT) == 2) {
                __half2 h0 = __floats2half2_rn(r[0], r[1]);
                __half2 h1 = __floats2half2_rn(r[2], r[3]);
                __half2 h2 = __floats2half2_rn(r[4], r[5]);
                __half2 h3 = __floats2half2_rn(r[6], r[7]);
                uint4 pk;
                pk.x = *(unsigned*)&h0; pk.y = *(unsigned*)&h1;
                pk.z = *(unsigned*)&h2; pk.w = *(unsigned*)&h3;
                *(uint4*)dst = pk;
            } else {
                *(float4*)((float*)dst) = make_float4(r[0], r[1], r[2], r[3]);
                *(float4*)((float*)dst + 4) = make_float4(r[4], r[5], r[6], r[7]);
            }
        } else {
            *(float2*)((float*)dst) = make_float2(r[0], r[1]);
        }
    }
}

// ---------------- fp32 gather for decoder-0 (16-row table) -> fp16 out -------
__global__ __launch_bounds__(256) void gat_gather_d0(const float* __restrict__ hsrc,
                                                     const float* __restrict__ es,
                                                     const float* __restrict__ ed,
                                                     const int* __restrict__ off,
                                                     const int* __restrict__ esrc,
                                                     const int* __restrict__ rmap,
                                                     const float* __restrict__ bias,
                                                     __half* __restrict__ out, int N) {
    int n = (blockIdx.x * blockDim.x + threadIdx.x) >> 6;
    int lane = threadIdx.x & 63;
    if (n >= N) return;
    int j0 = off[n], j1 = off[n + 1];
    float ed_h = (lane == 0) ? ed[n] : 0.f;
    float m_h = -INFINITY;
    for (int j = j0; j < j1; ++j) {
        int s = esrc[j];
        if (lane == 0) {
            float v = es[s] + ed_h;
            v = (v > 0.f) ? v : 0.2f * v;
            m_h = fmaxf(m_h, v);
        }
    }
    float acc = 0.f, den_h = 0.f;
    for (int j = j0; j < j1; ++j) {
        int s = esrc[j];
        float pm = 0.f;
        if (lane == 0) {
            float v = es[s] + ed_h;
            v = (v > 0.f) ? v : 0.2f * v;
            pm = expf(v - m_h);
            den_h += pm;
        }
        float a = __shfl(pm, 0);
        acc += a * hsrc[(size_t)rmap[s] * 64 + lane];
    }
    float dv = __shfl(den_h, 0) + 1e-16f;
    float o = acc / dv + bias[lane];
    o = fmaxf(o, 0.f);
    out[(size_t)n * 64 + lane] = __float2half(o);
}

// ---------------- pooling ----------------
__global__ __launch_bounds__(256) void gate_kernel(const __half* __restrict__ h,
                                                   const float* __restrict__ w1,
                                                   const float* __restrict__ b1,
                                                   const float* __restrict__ w2,
                                                   const float* __restrict__ b2,
                                                   float* __restrict__ gate, int N) {
    int n = (blockIdx.x * blockDim.x + threadIdx.x) >> 6;
    int lane = threadIdx.x & 63;
    if (n >= N) return;
    float hv = __half2float(h[(size_t)n * 64 + lane]);
    float t = b1[lane];
    for (int c = 0; c < 64; ++c) t += __shfl(hv, c) * w1[c * 64 + lane];
    t = fmaxf(t, 0.f);
    float g = t * w2[lane];
#pragma unroll
    for (int o = 32; o; o >>= 1) g += __shfl_xor(g, o);
    g += b2[0];
    if (lane == 0) gate[n] = g;
}

__global__ __launch_bounds__(256) void gmax_kernel(const float* __restrict__ gate,
                                                   const int* __restrict__ batch,
                                                   unsigned* __restrict__ gm, int N) {
    __shared__ unsigned smax[16];
    int t = threadIdx.x;
    if (t < 16) smax[t] = 0u;
    __syncthreads();
    for (int i = blockIdx.x * blockDim.x + t; i < N; i += gridDim.x * blockDim.x)
        atomicMax(&smax[batch[i]], f2o(gate[i]));
    __syncthreads();
    if (t < 16 && smax[t]) atomicMax(&gm[t], smax[t]);
}

__global__ __launch_bounds__(256) void pool_p(const float* __restrict__ gate,
                                              const unsigned* __restrict__ gm,
                                              const int* __restrict__ batch,
                                              float* __restrict__ pg,
                                              float* __restrict__ gden, int N) {
    __shared__ float part[16];
    int t = threadIdx.x;
    if (t < 16) part[t] = 0.f;
    __syncthreads();
    int n = blockIdx.x * blockDim.x + t;
    if (n < N) {
        int b = batch[n];
        unsigned u = gm[b];
        float mf = u ? o2f(u) : 0.f;
        float p = expf(gate[n] - mf);
        pg[n] = p;
        atomicAdd(&part[b], p);
    }
    __syncthreads();
    if (t < 16 && part[t] != 0.f) atomicAdd(&gden[t], part[t]);
}

#define NODES_PER_WAVE 128
__global__ __launch_bounds__(256) void pool_sum(const __half* __restrict__ h,
                                                const float* __restrict__ pg,
                                                const int* __restrict__ batch,
                                                float* __restrict__ pooled, int N) {
    int w = (blockIdx.x * blockDim.x + threadIdx.x) >> 6;
    int lane = threadIdx.x & 63;
    int start = w * NODES_PER_WAVE;
    if (start >= N) return;
    int curg = batch[start];
    float acc = 0.f;
    for (int i = 0; i < NODES_PER_WAVE; ++i) {
        int n = start + i;
        if (n >= N) break;
        int g = batch[n];
        if (g != curg) {
            atomicAdd(&pooled[curg * 64 + lane], acc);
            acc = 0.f;
            curg = g;
        }
        acc += pg[n] * __half2float(h[(size_t)n * 64 + lane]);
    }
    atomicAdd(&pooled[curg * 64 + lane], acc);
}

__global__ void dec_prep(const float* __restrict__ pooled, const float* __restrict__ gden,
                         const float* __restrict__ Wd0, const float* __restrict__ asd,
                         const float* __restrict__ add, float* __restrict__ hd016,
                         float* __restrict__ es16, float* __restrict__ ed16) {
    int g = blockIdx.x;
    int lane = threadIdx.x;
    float pn = pooled[g * 64 + lane] / (gden[g] + 1e-16f);
    float o = 0.f;
    for (int c = 0; c < 64; ++c) o += __shfl(pn, c) * Wd0[c * 64 + lane];
    hd016[g * 64 + lane] = o;
    float s = o * asd[lane], d = o * add[lane];
#pragma unroll
    for (int off = 32; off; off >>= 1) {
        s += __shfl_xor(s, off);
        d += __shfl_xor(d, off);
    }
    if (lane == 0) {
        es16[g] = s;
        ed16[g] = d;
    }
}

__global__ void expand_scores(const int* __restrict__ batch,
                              const float* __restrict__ es16,
                              const float* __restrict__ ed16,
                              float* __restrict__ esd,
                              float* __restrict__ edd, int N) {
    int n = blockIdx.x * blockDim.x + threadIdx.x;
    if (n >= N) return;
    int g = batch[n];
    esd[n] = es16[g];
    edd[n] = ed16[g];
}

// ---------------- host ----------------
static inline int cdiv(int a, int b) { return (a + b - 1) / b; }

extern "C" void kernel_launch(void* const* d_in, const int* in_sizes, int n_in,
                              void* d_out, int out_size, void* d_ws, size_t ws_size,
                              hipStream_t stream) {
    const float* x      = (const float*)d_in[0];
    const int*   ei     = (const int*)  d_in[1];
    const int*   batch  = (const int*)  d_in[2];
    const float* W_e0   = (const float*)d_in[3];
    const float* a_s_e0 = (const float*)d_in[4];
    const float* a_d_e0 = (const float*)d_in[5];
    const float* b_e0   = (const float*)d_in[6];
    const float* W_e1   = (const float*)d_in[7];
    const float* a_s_e1 = (const float*)d_in[8];
    const float* a_d_e1 = (const float*)d_in[9];
    const float* b_e1   = (const float*)d_in[10];
    const float* W_d0   = (const float*)d_in[11];
    const float* a_s_d0 = (const float*)d_in[12];
    const float* a_d_d0 = (const float*)d_in[13];
    const float* b_d0   = (const float*)d_in[14];
    const float* W_d1   = (const float*)d_in[15];
    const float* a_s_d1 = (const float*)d_in[16];
    const float* a_d_d1 = (const float*)d_in[17];
    const float* b_d1   = (const float*)d_in[18];
    const float* g_w1   = (const float*)d_in[19];
    const float* g_b1   = (const float*)d_in[20];
    const float* g_w2   = (const float*)d_in[21];
    const float* g_b2   = (const float*)d_in[22];

    const int N    = in_sizes[2];
    const int E    = in_sizes[1] / 2;
    const int Etot = E + N;
    const int Din  = in_sizes[0] / N;  // 128

    char* w = (char*)d_ws;
    size_t o = 0;
    auto alloc = [&](size_t bytes) -> void* {
        void* p = w + o;
        o = (o + bytes + 255) & ~(size_t)255;
        return p;
    };
    __half*   h16    = (__half*)  alloc((size_t)N * 512 * 2);
    __half*   x16    = (__half*)  alloc((size_t)N * Din * 2);
    __half*   bufA   = (__half*)  alloc((size_t)N * 64 * 2);
    __half*   bufB   = (__half*)  alloc((size_t)N * 64 * 2);
    __half*   wt_e0  = (__half*)  alloc((size_t)512 * 128 * 2);
    __half*   wt_e1  = (__half*)  alloc((size_t)512 * 64 * 2);
    __half*   wt_d1  = (__half*)  alloc((size_t)128 * 64 * 2);
    float*    es     = (float*)   alloc((size_t)N * 8 * 4);
    float*    ed     = (float*)   alloc((size_t)N * 8 * 4);
    float*    gate   = (float*)   alloc((size_t)N * 4);
    float*    pg     = (float*)   alloc((size_t)N * 4);
    int*      off    = (int*)     alloc((size_t)(N + 1) * 4);
    int*      cnt    = (int*)     alloc((size_t)N * 4);
    int*      esrc   = (int*)     alloc((size_t)Etot * 4);
    int*      bsum   = (int*)     alloc(256 * 4);
    unsigned* gm     = (unsigned*)alloc(16 * 4);
    float*    gden   = (float*)   alloc(16 * 4);
    float*    pooled = (float*)   alloc(16 * 64 * 4);
    float*    hd016  = (float*)   alloc(16 * 64 * 4);
    float*    es16   = (float*)   alloc(16 * 4);
    float*    ed16   = (float*)   alloc(16 * 4);
    (void)ws_size; (void)n_in; (void)out_size;

    float* esd = gate;
    float* edd = pg;

    const int nodeWaveGrid = cdiv(N, 4);
    const int edgeGrid     = cdiv(Etot, TB);
    const int scanBlocks   = cdiv(N, 256);

    // ---- CSR ----
    hipMemsetAsync(cnt, 0, (size_t)N * 4, stream);
    csr_count<<<edgeGrid, TB, 0, stream>>>(ei, E, Etot, cnt);
    scan_phase1<<<scanBlocks, 256, 0, stream>>>(cnt, esrc /*temp incl*/, bsum, N);
    scan_phase2<<<1, 256, 0, stream>>>(bsum, scanBlocks);
    scan_phase3<<<scanBlocks, 256, 0, stream>>>(esrc, bsum, off, N);
    hipMemsetAsync(cnt, 0, (size_t)N * 4, stream);
    csr_fill<<<edgeGrid, TB, 0, stream>>>(ei, E, Etot, off, cnt, esrc);

    // ---- fp16 prep ----
    cast_f2h<<<cdiv(N * Din / 2, TB), TB, 0, stream>>>(x, x16, N * Din);
    transpose_cast<<<cdiv(512 * 128, TB), TB, 0, stream>>>(W_e0, wt_e0, Din, 512);
    transpose_cast<<<cdiv(512 * 64, TB), TB, 0, stream>>>(W_e1, wt_e1, 64, 512);
    transpose_cast<<<cdiv(128 * 64, TB), TB, 0, stream>>>(W_d1, wt_d1, 64, 128);

    // ---- encoder layer 0 (H=8, relu) ----
    {
        dim3 grid(512 / 64, cdiv(N, 64));
        gemm_mfma<128><<<grid, TB, 0, stream>>>(x16, wt_e0, h16, N, 512);
    }
    attn_scores_h<8, 64><<<nodeWaveGrid, TB, 0, stream>>>(h16, a_s_e0, a_d_e0, es, ed, N);
    gat_gather_h<8, 64, true, __half><<<nodeWaveGrid, TB, 0, stream>>>(
        h16, es, ed, off, esrc, b_e0, bufA, N);

    // ---- encoder layer 1 (H=8) ----
    {
        dim3 grid(512 / 64, cdiv(N, 64));
        gemm_mfma<64><<<grid, TB, 0, stream>>>(bufA, wt_e1, h16, N, 512);
    }
    attn_scores_h<8, 64><<<nodeWaveGrid, TB, 0, stream>>>(h16, a_s_e1, a_d_e1, es, ed, N);
    gat_gather_h<8, 64, false, __half><<<nodeWaveGrid, TB, 0, stream>>>(
        h16, es, ed, off, esrc, b_e1, bufB, N);

    // ---- pooling ----
    hipMemsetAsync(gm, 0, 16 * 4, stream);
    hipMemsetAsync(gden, 0, 16 * 4, stream);
    hipMemsetAsync(pooled, 0, 16 * 64 * 4, stream);
    gate_kernel<<<nodeWaveGrid, TB, 0, stream>>>(bufB, g_w1, g_b1, g_w2, g_b2, gate, N);
    gmax_kernel<<<256, TB, 0, stream>>>(gate, batch, gm, N);
    pool_p<<<cdiv(N, TB), TB, 0, stream>>>(gate, gm, batch, pg, gden, N);
    pool_sum<<<cdiv(cdiv(N, NODES_PER_WAVE), 4), TB, 0, stream>>>(bufB, pg, batch, pooled, N);
    dec_prep<<<16, 64, 0, stream>>>(pooled, gden, W_d0, a_s_d0, a_d_d0, hd016, es16, ed16);
    expand_scores<<<cdiv(N, TB), TB, 0, stream>>>(batch, es16, ed16, esd, edd, N);

    // ---- decoder layer 0 (H=1, relu): gather from 16-row hd016 via batch[src] ----
    gat_gather_d0<<<nodeWaveGrid, TB, 0, stream>>>(
        hd016, esd, edd, off, esrc, batch, b_d0, bufA, N);

    // ---- decoder layer 1 (H=1, C=128) -> d_out ----
    {
        dim3 grid(128 / 64, cdiv(N, 64));
        gemm_mfma<64><<<grid, TB, 0, stream>>>(bufA, wt_d1, h16, N, 128);
    }
    attn_scores_h<1, 128><<<nodeWaveGrid, TB, 0, stream>>>(h16, a_s_d1, a_d_d1, esd, edd, N);
    gat_gather_h<1, 128, false, float><<<nodeWaveGrid, TB, 0, stream>>>(
        h16, esd, edd, off, esrc, b_d1, (float*)d_out, N);
}